// Round 4
// baseline (1835.984 us; speedup 1.0000x reference)
//
#include <hip/hip_runtime.h>

#define DEVINL __device__ __forceinline__

typedef unsigned short u16;
typedef __attribute__((ext_vector_type(8))) short bf16x8;   // 8 bf16 = 4 VGPRs (MFMA A/B frag)
typedef __attribute__((ext_vector_type(4))) float f32x4;     // MFMA C/D frag
typedef __attribute__((ext_vector_type(4))) unsigned short u16x4;

// B=4, S=1024, HID=4096, NH=32, NKV=8, HD=128, FF=11008

DEVINL float bf2f(u16 u) { union { unsigned i; float f; } x; x.i = ((unsigned)u) << 16; return x.f; }
DEVINL u16 f2bf(float f) {                       // round-to-nearest-even
  union { float f; unsigned i; } x; x.f = f;
  unsigned r = x.i + 0x7fffu + ((x.i >> 16) & 1u);
  return (u16)(r >> 16);
}

// async global->LDS, 16B per lane; lds base must be wave-uniform (HW: base + lane*16)
DEVINL void async16(u16* lds, const u16* g) {
  __builtin_amdgcn_global_load_lds((const __attribute__((address_space(1))) unsigned*)g,
                                   (__attribute__((address_space(3))) unsigned*)lds, 16, 0, 0);
}

// ---------------- weight convert + transpose: in fp32 [K,N] -> out bf16 [N,K] ----------------
__global__ __launch_bounds__(256) void conv_t(const float* __restrict__ in,
                                              u16* __restrict__ out, int K, int N) {
  __shared__ float tile[64][65];
  int k0 = blockIdx.y << 6, n0 = blockIdx.x << 6;
  int t = threadIdx.x;
  int r = t >> 4, c4 = (t & 15) << 2;
  #pragma unroll
  for (int it = 0; it < 4; it++) {
    int row = r + it*16;
    f32x4 v = *(const f32x4*)(in + (size_t)(k0 + row)*N + n0 + c4);
    tile[row][c4+0] = v[0]; tile[row][c4+1] = v[1];
    tile[row][c4+2] = v[2]; tile[row][c4+3] = v[3];
  }
  __syncthreads();
  #pragma unroll
  for (int it = 0; it < 4; it++) {
    int nrow = r + it*16;
    u16x4 ov;
    #pragma unroll
    for (int e = 0; e < 4; e++) ov[e] = f2bf(tile[c4+e][nrow]);
    *(u16x4*)(out + (size_t)(n0 + nrow)*K + k0 + c4) = ov;
  }
}

// ---------------- RMSNorm: fp32 in [4096 rows x 4096] -> bf16 out ----------------
__global__ __launch_bounds__(256) void rmsnorm_kernel(const float* __restrict__ x,
                                                      const float* __restrict__ w,
                                                      u16* __restrict__ out) {
  int row = blockIdx.x, t = threadIdx.x;
  const float* xr = x + (size_t)row * 4096;
  f32x4 v[4];
  float ss = 0.f;
  #pragma unroll
  for (int i = 0; i < 4; i++) {
    v[i] = *(const f32x4*)(xr + (t + 256*i)*4);
    ss += v[i][0]*v[i][0] + v[i][1]*v[i][1] + v[i][2]*v[i][2] + v[i][3]*v[i][3];
  }
  #pragma unroll
  for (int d = 1; d < 64; d <<= 1) ss += __shfl_xor(ss, d, 64);
  __shared__ float ps[4];
  if ((t & 63) == 0) ps[t >> 6] = ss;
  __syncthreads();
  float scale = rsqrtf((ps[0]+ps[1]+ps[2]+ps[3]) * (1.f/4096.f) + 1e-6f);
  #pragma unroll
  for (int i = 0; i < 4; i++) {
    f32x4 wv = *(const f32x4*)(w + (t + 256*i)*4);
    u16x4 o;
    #pragma unroll
    for (int e = 0; e < 4; e++) o[e] = f2bf(v[i][e] * scale * wv[e]);
    *(u16x4*)(out + (size_t)row*4096 + (t + 256*i)*4) = o;
  }
}

// ---------------- RoPE in-place on q [tok,32*128] & k [tok,8*128]; q gets 1/sqrt(HD) ----------------
__global__ __launch_bounds__(256) void rope_kernel(u16* __restrict__ q, u16* __restrict__ k) {
  int tok = blockIdx.x;            // b*1024 + s ; position id == s
  int s = tok & 1023;
  __shared__ float cs[64], sn[64];
  int t = threadIdx.x;
  if (t < 64) {
    float inv = __expf(-(float)t * 0.14391156934f);  // ln(10000)/64
    float ang = (float)s * inv;
    cs[t] = cosf(ang); sn[t] = sinf(ang);
  }
  __syncthreads();
  const float qscale = 0.08838834764831845f;          // 1/sqrt(128)
  size_t qbase = (size_t)tok * 4096;
  #pragma unroll
  for (int it = 0; it < 8; it++) {
    int item = t + it*256; int h = item >> 6, j = item & 63;
    size_t i0 = qbase + h*128 + j;
    float x1 = bf2f(q[i0]), x2 = bf2f(q[i0+64]);
    float c = cs[j], si = sn[j];
    q[i0]    = f2bf((x1*c - x2*si) * qscale);
    q[i0+64] = f2bf((x2*c + x1*si) * qscale);
  }
  size_t kbase = (size_t)tok * 1024;
  #pragma unroll
  for (int it = 0; it < 2; it++) {
    int item = t + it*256; int h = item >> 6, j = item & 63;
    size_t i0 = kbase + h*128 + j;
    float x1 = bf2f(k[i0]), x2 = bf2f(k[i0+64]);
    float c = cs[j], si = sn[j];
    k[i0]    = f2bf(x1*c - x2*si);
    k[i0+64] = f2bf(x2*c + x1*si);
  }
}

// ---------------- V transpose per (b,kvh): [1024 x 128] -> vt [128 x 1024] ----------------
__global__ __launch_bounds__(256) void vtrans(const u16* __restrict__ v, u16* __restrict__ vt) {
  __shared__ u16 tile[32][33];
  int bh = blockIdx.z; int b = bh >> 3, kvh = bh & 7;
  int d0 = blockIdx.x << 5, s0 = blockIdx.y << 5;
  int tx = threadIdx.x, ty = threadIdx.y;   // (32,8)
  for (int r = ty; r < 32; r += 8)
    tile[r][tx] = v[(size_t)(b*1024 + s0 + r)*1024 + kvh*128 + d0 + tx];
  __syncthreads();
  for (int r = ty; r < 32; r += 8)
    vt[(size_t)((b*8 + kvh)*128 + d0 + r)*1024 + s0 + tx] = tile[tx][r];
}

// ---------------- 128-tile GEMM (kept for K/V projections: N=1024 too small for 256-tiles) ----------------
template<int EPI>
__global__ __launch_bounds__(256, 2) void gemm_bt(
    const u16* __restrict__ A, const u16* __restrict__ Bt,
    void* __restrict__ Cv, const float* __restrict__ resid,
    const u16* __restrict__ gate, int M, int N, int K) {
  __shared__ u16 As[128*64];
  __shared__ u16 Bs[128*64];
  int nwg = gridDim.x;
  int bid = (int)blockIdx.x;
  int cpx = nwg >> 3;
  int swz = (bid & 7) * cpx + (bid >> 3);
  int mt = M >> 7;
  int m0 = (swz % mt) << 7;
  int n0 = (swz / mt) << 7;
  int tid = threadIdx.x;
  int lane = tid & 63, wave = tid >> 6;
  int wm = wave >> 1, wn = wave & 1;

  f32x4 acc[4][4];
  f32x4 zero = {0.f, 0.f, 0.f, 0.f};
  #pragma unroll
  for (int i = 0; i < 4; i++)
    #pragma unroll
    for (int j = 0; j < 4; j++) acc[i][j] = zero;

  int arow[4], acolb[4];
  #pragma unroll
  for (int i = 0; i < 4; i++) {
    int c = i*256 + tid;
    arow[i]  = c >> 3;
    acolb[i] = ((c & 7) * 16) ^ ((arow[i] & 7) << 4);
  }

  int nsteps = K >> 6;
  for (int t = 0; t < nsteps; t++) {
    int k0 = t << 6;
    #pragma unroll
    for (int i = 0; i < 4; i++) {
      async16(As + i*2048 + wave*512, A  + (size_t)(m0 + arow[i])*K + k0 + (acolb[i] >> 1));
      async16(Bs + i*2048 + wave*512, Bt + (size_t)(n0 + arow[i])*K + k0 + (acolb[i] >> 1));
    }
    __syncthreads();
    #pragma unroll
    for (int ks = 0; ks < 2; ks++) {
      bf16x8 af[4], bfr[4];
      int c2 = (ks*32 + (lane >> 4)*8) * 2;
      #pragma unroll
      for (int mf = 0; mf < 4; mf++) {
        int r = wm*64 + mf*16 + (lane & 15);
        af[mf] = *(const bf16x8*)(As + r*64 + ((c2 ^ ((r & 7) << 4)) >> 1));
      }
      #pragma unroll
      for (int nf = 0; nf < 4; nf++) {
        int r = wn*64 + nf*16 + (lane & 15);
        bfr[nf] = *(const bf16x8*)(Bs + r*64 + ((c2 ^ ((r & 7) << 4)) >> 1));
      }
      #pragma unroll
      for (int mf = 0; mf < 4; mf++)
        #pragma unroll
        for (int nf = 0; nf < 4; nf++)
          acc[mf][nf] = __builtin_amdgcn_mfma_f32_16x16x32_bf16(af[mf], bfr[nf], acc[mf][nf], 0, 0, 0);
    }
    __syncthreads();
  }

  #pragma unroll
  for (int mf = 0; mf < 4; mf++)
    #pragma unroll
    for (int nf = 0; nf < 4; nf++)
      #pragma unroll
      for (int j = 0; j < 4; j++) {
        int rr = m0 + wm*64 + mf*16 + (lane >> 4)*4 + j;
        int cc = n0 + wn*64 + nf*16 + (lane & 15);
        size_t idx = (size_t)rr * N + cc;
        float v = acc[mf][nf][j];
        if constexpr (EPI == 0) {
          ((u16*)Cv)[idx] = f2bf(v);
        } else if constexpr (EPI == 1) {
          ((float*)Cv)[idx] = v + resid[idx];
        } else {
          float g = bf2f(gate[idx]);
          float sg = g / (1.f + __expf(-g));
          ((u16*)Cv)[idx] = f2bf(sg * v);
        }
      }
}

// ---------------- 256x256 GEMM, m201-faithful 4-phase/K-tile schedule ----------------
// 512 thr = 8 waves (2M x 4N), wave out 128x64. BK=64. LDS = 2 bufs x (A 32KB | B 32KB) = 128 KiB,
// organized as 16KB QUADRANT REGIONS: A-q (rows used by qm-phases: [hw][64 rows][64 K]), B-q likewise.
// Phase p = C-quadrant (qm,qn): {ds-read reg subtile (12/4/8/0 reads), stage ONE region of tile k+1
// into buf^1 (2 gloads), barrier, lgkmcnt(0), setprio(1), 16 MFMA, setprio(0), counted vmcnt, barrier}.
// Stage order [Aq0,Bq0,Bq1,Aq1] = consumption order; region writes land >=3 phase-barriers after that
// region's reads retired. vmcnt(4) at phases 1,2,4 retires exactly the region consumed next
// (FIFO-verified); 4-6 loads always in flight (never drains to 0 until last tile).
#define SB0() __builtin_amdgcn_sched_barrier(0)
#define MIDBAR() do { SB0(); __builtin_amdgcn_s_barrier(); \
  asm volatile("s_waitcnt lgkmcnt(0)" ::: "memory"); SB0(); } while (0)
#define MFMAQ2(qm, qn, afr, bq) do { \
  __builtin_amdgcn_s_setprio(1); \
  _Pragma("unroll") for (int mf_ = 0; mf_ < 4; mf_++) \
  _Pragma("unroll") for (int nf_ = 0; nf_ < 2; nf_++) \
  _Pragma("unroll") for (int ks_ = 0; ks_ < 2; ks_++) \
    acc[(qm)*4+mf_][(qn)*2+nf_] = __builtin_amdgcn_mfma_f32_16x16x32_bf16( \
        afr[mf_][ks_], bq[nf_][ks_], acc[(qm)*4+mf_][(qn)*2+nf_], 0, 0, 0); \
  __builtin_amdgcn_s_setprio(0); } while (0)

template<int EPI>
__global__ __launch_bounds__(512, 2) void gemm256(
    const u16* __restrict__ A, const u16* __restrict__ Bt,
    void* __restrict__ Cv, const float* __restrict__ resid,
    const u16* __restrict__ gate, int M, int N, int K) {
  extern __shared__ u16 lds[];              // [2 bufs][A: 2 q-regions | B: 2 q-regions], 8192 u16/region
  int nwg = gridDim.x, bid = (int)blockIdx.x;
  int cpx = nwg >> 3;
  int swz = (bid & 7) * cpx + (bid >> 3);   // XCD-contiguous chunks (T1); all grids %8==0
  int mt = M >> 8;
  int m0 = (swz % mt) << 8;
  int n0 = (swz / mt) << 8;
  int tid = threadIdx.x, lane = tid & 63, wave = tid >> 6;
  int wm = wave >> 2, wn = wave & 3;

  f32x4 acc[8][4];
  f32x4 zero = {0.f, 0.f, 0.f, 0.f};
  #pragma unroll
  for (int i = 0; i < 8; i++)
    #pragma unroll
    for (int j = 0; j < 4; j++) acc[i][j] = zero;

  // staging: region chunk c = wave*128 + j*64 + lane; lr=c>>3, cc=lane&7; swizzled source chunk
  int sCol = ((lane & 7) ^ (lane >> 3)) << 3;                // pre-swizzled global K-col (u16)
  int aRow = ((wave >> 2)*128) + (wave & 3)*16 + (lane >> 3);  // logical A row for region qm (+qm*64)
  int bRow = ((wave >> 1)*64)  + (wave & 1)*16 + (lane >> 3);  // logical B row for region qn (+qn*32)
  const u16* gA = A  + (size_t)(m0 + aRow) * K + sCol;
  const u16* gB = Bt + (size_t)(n0 + bRow) * K + sCol;
  size_t K8 = (size_t)8 * K, K32 = (size_t)32 * K, K64 = (size_t)64 * K;

  // fragment reads: within-region row = frag*16 + rA; stored chunk = logical ^ (row&7)
  int rA = lane & 15;
  int acol0 = (((lane >> 4)    ) ^ (rA & 7)) << 3;           // ks=0 (u16 units)
  int acol1 = (((lane >> 4) + 4) ^ (rA & 7)) << 3;           // ks=1

  bf16x8 af[4][2], b0[2][2], b1[2][2];

  auto stageAq = [&](int buf, int qm, int k0) {              // one 16KB region, 2 gloads/thread
    u16* d = lds + buf*32768 + qm*8192 + wave*1024;
    const u16* s = gA + (size_t)qm*K64 + k0;
    async16(d, s); async16(d + 512, s + K8);
  };
  auto stageBq = [&](int buf, int qn, int k0) {
    u16* d = lds + buf*32768 + 16384 + qn*8192 + wave*1024;
    const u16* s = gB + (size_t)qn*K32 + k0;
    async16(d, s); async16(d + 512, s + K8);
  };
  auto loadAq = [&](int buf, int qm) {                       // 8 ds_read_b128 into af
    const u16* base = lds + buf*32768 + qm*8192 + wm*4096 + rA*64;
    #pragma unroll
    for (int mf = 0; mf < 4; mf++) {
      af[mf][0] = *(const bf16x8*)(base + mf*1024 + acol0);
      af[mf][1] = *(const bf16x8*)(base + mf*1024 + acol1);
    }
  };
  auto loadBq = [&](int buf, int qn, bf16x8 (&bq)[2][2]) {   // 4 ds_read_b128
    const u16* base = lds + buf*32768 + 16384 + qn*8192 + wn*2048 + rA*64;
    #pragma unroll
    for (int nf = 0; nf < 2; nf++) {
      bq[nf][0] = *(const bf16x8*)(base + nf*1024 + acol0);
      bq[nf][1] = *(const bf16x8*)(base + nf*1024 + acol1);
    }
  };

  int nt = K >> 6;
  // prologue: stage tile 0 (consumption order); land Aq0+Bq0, leave Bq1+Aq1 in flight
  stageAq(0, 0, 0); stageBq(0, 0, 0); stageBq(0, 1, 0); stageAq(0, 1, 0);
  SB0();
  asm volatile("s_waitcnt vmcnt(4)" ::: "memory");
  SB0();
  __builtin_amdgcn_s_barrier();

  for (int k = 0; k < nt; k++) {
    int buf = k & 1, nbuf = buf ^ 1;
    bool pre = (k + 1) < nt;
    int k1 = (k + 1) << 6;
    // ---- phase 1: Q(0,0); 12 reads; stage Aq0(k+1)
    loadAq(buf, 0); loadBq(buf, 0, b0);
    if (pre) stageAq(nbuf, 0, k1);
    MIDBAR();
    MFMAQ2(0, 0, af, b0);
    SB0();
    if (pre) asm volatile("s_waitcnt vmcnt(4)" ::: "memory");  // retires Bq1(k) (needed ph2)
    else     asm volatile("s_waitcnt vmcnt(2)" ::: "memory");
    SB0(); __builtin_amdgcn_s_barrier();
    // ---- phase 2: Q(0,1); 4 reads; stage Bq0(k+1)
    loadBq(buf, 1, b1);
    if (pre) stageBq(nbuf, 0, k1);
    MIDBAR();
    MFMAQ2(0, 1, af, b1);
    SB0();
    if (pre) asm volatile("s_waitcnt vmcnt(4)" ::: "memory");  // retires Aq1(k) (needed ph3)
    else     asm volatile("s_waitcnt vmcnt(0)" ::: "memory");
    SB0(); __builtin_amdgcn_s_barrier();
    // ---- phase 3: Q(1,0); 8 reads; stage Bq1(k+1); no vmcnt
    loadAq(buf, 1);
    if (pre) stageBq(nbuf, 1, k1);
    MIDBAR();
    MFMAQ2(1, 0, af, b0);
    SB0(); __builtin_amdgcn_s_barrier();
    // ---- phase 4: Q(1,1); 0 reads; stage Aq1(k+1)
    if (pre) stageAq(nbuf, 1, k1);
    MIDBAR();
    MFMAQ2(1, 1, af, b1);
    SB0();
    if (pre) asm volatile("s_waitcnt vmcnt(4)" ::: "memory");  // retires Aq0,Bq0(k+1) (needed next ph1)
    SB0(); __builtin_amdgcn_s_barrier();
  }

  // C/D layout: col = lane&15, row = (lane>>4)*4 + j;  acc[i] row = i*16, acc[][jn] col = jn*16
  #pragma unroll
  for (int mf = 0; mf < 8; mf++)
    #pragma unroll
    for (int nf = 0; nf < 4; nf++)
      #pragma unroll
      for (int j = 0; j < 4; j++) {
        int rr = m0 + wm*128 + mf*16 + (lane >> 4)*4 + j;
        int cc = n0 + wn*64 + nf*16 + (lane & 15);
        size_t idx = (size_t)rr * N + cc;
        float v = acc[mf][nf][j];
        if constexpr (EPI == 0) {
          ((u16*)Cv)[idx] = f2bf(v);
        } else if constexpr (EPI == 1) {
          ((float*)Cv)[idx] = v + resid[idx];
        } else {
          float g = bf2f(gate[idx]);
          float sg = g / (1.f + __expf(-g));
          ((u16*)Cv)[idx] = f2bf(sg * v);
        }
      }
}

// ---------------- Flash attention, causal, GQA 4:1 ----------------
__global__ __launch_bounds__(256, 2) void attn_kernel(
    const u16* __restrict__ q, const u16* __restrict__ k,
    const u16* __restrict__ vt, u16* __restrict__ out) {
  __shared__ u16 Ks[64*128];
  __shared__ u16 Vs[128*64];
  __shared__ u16 Ps[4*16*64];
  int bid = blockIdx.x;
  int qt = bid & 15;
  int h  = (bid >> 4) & 31;
  int b  = bid >> 9;
  int kvh = h >> 2;
  int tid = threadIdx.x, lane = tid & 63, wave = tid >> 6;
  int q0 = qt << 6;

  bf16x8 qf[4];
  {
    const u16* qb_ = q + (size_t)(b*1024 + q0 + wave*16 + (lane & 15))*4096 + h*128 + (lane >> 4)*8;
    #pragma unroll
    for (int ks = 0; ks < 4; ks++) qf[ks] = *(const bf16x8*)(qb_ + ks*32);
  }
  f32x4 o[8];
  f32x4 zero = {0.f,0.f,0.f,0.f};
  #pragma unroll
  for (int i = 0; i < 8; i++) o[i] = zero;
  float m[4] = {-1e30f,-1e30f,-1e30f,-1e30f};
  float l[4] = {0.f,0.f,0.f,0.f};

  int kr[4], kc[4], vr[4], vc[4];
  #pragma unroll
  for (int i = 0; i < 4; i++) {
    int c = i*256 + tid;
    kr[i] = c >> 4; kc[i] = ((c & 15)*16) ^ ((kr[i] & 7) << 4);
    vr[i] = c >> 3; vc[i] = ((c & 7)*16)  ^ ((vr[i] & 7) << 4);
  }

  for (int t = 0; t <= qt; t++) {
    int kv0 = t << 6;
    #pragma unroll
    for (int i = 0; i < 4; i++) {
      async16(Ks + i*2048 + wave*512, k  + (size_t)(b*1024 + kv0 + kr[i])*1024 + kvh*128 + (kc[i] >> 1));
      async16(Vs + i*2048 + wave*512, vt + (size_t)((b*8 + kvh)*128 + vr[i])*1024 + kv0 + (vc[i] >> 1));
    }
    __syncthreads();

    f32x4 s[4];
    #pragma unroll
    for (int nf = 0; nf < 4; nf++) {
      s[nf] = zero;
      #pragma unroll
      for (int ks = 0; ks < 4; ks++) {
        int r = nf*16 + (lane & 15);
        int c2 = (ks*32 + (lane >> 4)*8)*2;
        bf16x8 kf = *(const bf16x8*)(Ks + r*128 + ((c2 ^ ((r & 7) << 4)) >> 1));
        s[nf] = __builtin_amdgcn_mfma_f32_16x16x32_bf16(qf[ks], kf, s[nf], 0, 0, 0);
      }
    }
    if (t == qt) {
      #pragma unroll
      for (int nf = 0; nf < 4; nf++)
        #pragma unroll
        for (int j = 0; j < 4; j++) {
          int cc = nf*16 + (lane & 15);
          int rr = wave*16 + (lane >> 4)*4 + j;
          if (cc > rr) s[nf][j] = -1e30f;
        }
    }
    #pragma unroll
    for (int j = 0; j < 4; j++) {
      float mx = fmaxf(fmaxf(s[0][j], s[1][j]), fmaxf(s[2][j], s[3][j]));
      #pragma unroll
      for (int d = 1; d < 16; d <<= 1) mx = fmaxf(mx, __shfl_xor(mx, d, 64));
      float mn = fmaxf(m[j], mx);
      float f = __expf(m[j] - mn);
      m[j] = mn;
      float ssum = 0.f;
      #pragma unroll
      for (int nf = 0; nf < 4; nf++) {
        float p = __expf(s[nf][j] - mn);
        s[nf][j] = p; ssum += p;
      }
      #pragma unroll
      for (int d = 1; d < 16; d <<= 1) ssum += __shfl_xor(ssum, d, 64);
      l[j] = l[j]*f + ssum;
      #pragma unroll
      for (int nf = 0; nf < 8; nf++) o[nf][j] *= f;
    }
    #pragma unroll
    for (int nf = 0; nf < 4; nf++)
      #pragma unroll
      for (int j = 0; j < 4; j++) {
        int rr = (lane >> 4)*4 + j;
        int cb = ((nf*16 + (lane & 15))*2) ^ ((rr & 7) << 4);
        Ps[wave*1024 + rr*64 + (cb >> 1)] = f2bf(s[nf][j]);
      }
    #pragma unroll
    for (int ks2 = 0; ks2 < 2; ks2++) {
      int mr = lane & 15;
      int c2 = (ks2*32 + (lane >> 4)*8)*2;
      bf16x8 pa = *(const bf16x8*)(Ps + wave*1024 + mr*64 + ((c2 ^ ((mr & 7) << 4)) >> 1));
      #pragma unroll
      for (int nf = 0; nf < 8; nf++) {
        int d = nf*16 + (lane & 15);
        bf16x8 vf = *(const bf16x8*)(Vs + d*64 + ((c2 ^ ((d & 7) << 4)) >> 1));
        o[nf] = __builtin_amdgcn_mfma_f32_16x16x32_bf16(pa, vf, o[nf], 0, 0, 0);
      }
    }
    __syncthreads();
  }

  float inv[4];
  #pragma unroll
  for (int j = 0; j < 4; j++) inv[j] = 1.f / l[j];
  u16* ob = out + (size_t)(b*1024 + q0 + wave*16)*4096 + h*128;
  #pragma unroll
  for (int nf = 0; nf < 8; nf++)
    #pragma unroll
    for (int j = 0; j < 4; j++) {
      int rr = (lane >> 4)*4 + j;
      int cc = nf*16 + (lane & 15);
      ob[(size_t)rr*4096 + cc] = f2bf(o[nf][j] * inv[j]);
    }
}

// ---------------- driver ----------------
extern "C" void kernel_launch(void* const* d_in, const int* in_sizes, int n_in,
                              void* d_out, int out_size, void* d_ws, size_t ws_size,
                              hipStream_t stream) {
  (void)in_sizes; (void)n_in; (void)out_size;
  const float* hidden = (const float*)d_in[0];
  const float* Wq  = (const float*)d_in[3];
  const float* Wk  = (const float*)d_in[4];
  const float* Wv  = (const float*)d_in[5];
  const float* Wo  = (const float*)d_in[6];
  const float* ln1 = (const float*)d_in[7];
  const float* ln2 = (const float*)d_in[8];
  const float* Wg  = (const float*)d_in[9];
  const float* Wu  = (const float*)d_in[10];
  const float* Wd  = (const float*)d_in[11];
  float* out = (float*)d_out;

  char* ws = (char*)d_ws;
  size_t off = 0;
  auto alloc = [&](size_t b) { char* p = ws + off; off += (b + 4095) & ~(size_t)4095; return p; };
  u16*  W1   = (u16*)alloc(90177536);
  u16*  h1   = (u16*)alloc(33554432);
  u16*  qb   = (u16*)alloc(33554432);
  u16*  kb   = (u16*)alloc(8388608);
  u16*  vb   = (u16*)alloc(8388608);
  u16*  vtb  = (u16*)alloc(8388608);
  float* hmid = (float*)alloc(67108864);
  u16*  gb   = (u16*)alloc(90177536);
  if (off > ws_size) return;

  u16* wqT = W1;
  u16* wkT = W1 + 16777216;
  u16* wvT = wkT + 4194304;

  hipFuncSetAttribute((const void*)gemm256<0>, hipFuncAttributeMaxDynamicSharedMemorySize, 131072);
  hipFuncSetAttribute((const void*)gemm256<1>, hipFuncAttributeMaxDynamicSharedMemorySize, 131072);
  hipFuncSetAttribute((const void*)gemm256<2>, hipFuncAttributeMaxDynamicSharedMemorySize, 131072);

  dim3 blk(256);
  // 1) QKV weights -> bf16 transposed
  conv_t<<<dim3(64, 64),  blk, 0, stream>>>(Wq, wqT, 4096, 4096);
  conv_t<<<dim3(16, 64),  blk, 0, stream>>>(Wk, wkT, 4096, 1024);
  conv_t<<<dim3(16, 64),  blk, 0, stream>>>(Wv, wvT, 4096, 1024);
  // 2) norm1
  rmsnorm_kernel<<<4096, blk, 0, stream>>>(hidden, ln1, h1);
  // 3) QKV projections (Q on 256-tile; K/V too narrow -> 128-tile)
  gemm256<0><<<256, 512, 131072, stream>>>(h1, wqT, qb, nullptr, nullptr, 4096, 4096, 4096);
  gemm_bt<0><<<256, blk, 0, stream>>>(h1, wkT, kb, nullptr, nullptr, 4096, 1024, 4096);
  gemm_bt<0><<<256, blk, 0, stream>>>(h1, wvT, vb, nullptr, nullptr, 4096, 1024, 4096);
  // 4) RoPE (q also gets 1/sqrt(HD))
  rope_kernel<<<4096, blk, 0, stream>>>(qb, kb);
  // 5) V transpose
  vtrans<<<dim3(4, 32, 32), dim3(32, 8), 0, stream>>>(vb, vtb);
  // 6) attention -> h1
  attn_kernel<<<2048, blk, 0, stream>>>(qb, kb, vtb, h1);
  // 7) Wo + residual -> hmid (fp32)
  conv_t<<<dim3(64, 64), blk, 0, stream>>>(Wo, W1, 4096, 4096);
  gemm256<1><<<256, 512, 131072, stream>>>(h1, W1, hmid, hidden, nullptr, 4096, 4096, 4096);
  // 8) norm2 -> qb
  rmsnorm_kernel<<<4096, blk, 0, stream>>>(hmid, ln2, qb);
  // 9) gate
  conv_t<<<dim3(172, 64), blk, 0, stream>>>(Wg, W1, 4096, 11008);
  gemm256<0><<<688, 512, 131072, stream>>>(qb, W1, gb, nullptr, nullptr, 4096, 11008, 4096);
  // 10) up, epilogue act = silu(gate)*up (in place over gb)
  conv_t<<<dim3(172, 64), blk, 0, stream>>>(Wu, W1, 4096, 11008);
  gemm256<2><<<688, 512, 131072, stream>>>(qb, W1, gb, nullptr, gb, 4096, 11008, 4096);
  // 11) down + residual -> d_out (fp32)
  conv_t<<<dim3(64, 172), blk, 0, stream>>>(Wd, W1, 11008, 4096);
  gemm256<1><<<256, 512, 131072, stream>>>(gb, W1, out, hmid, nullptr, 4096, 4096, 11008);
}

// Round 5
// 1819.152 us; speedup vs baseline: 1.0093x; 1.0093x over previous
//
#include <hip/hip_runtime.h>

#define DEVINL __device__ __forceinline__

typedef unsigned short u16;
typedef __attribute__((ext_vector_type(8))) short bf16x8;   // 8 bf16 = 4 VGPRs (MFMA A/B frag)
typedef __attribute__((ext_vector_type(4))) float f32x4;     // MFMA C/D frag
typedef __attribute__((ext_vector_type(4))) unsigned short u16x4;

// B=4, S=1024, HID=4096, NH=32, NKV=8, HD=128, FF=11008

DEVINL float bf2f(u16 u) { union { unsigned i; float f; } x; x.i = ((unsigned)u) << 16; return x.f; }
DEVINL u16 f2bf(float f) {                       // round-to-nearest-even
  union { float f; unsigned i; } x; x.f = f;
  unsigned r = x.i + 0x7fffu + ((x.i >> 16) & 1u);
  return (u16)(r >> 16);
}

// async global->LDS, 16B per lane; lds base must be wave-uniform (HW: base + lane*16)
DEVINL void async16(u16* lds, const u16* g) {
  __builtin_amdgcn_global_load_lds((const __attribute__((address_space(1))) unsigned*)g,
                                   (__attribute__((address_space(3))) unsigned*)lds, 16, 0, 0);
}

// ---------------- weight convert + transpose: in fp32 [K,N] -> out bf16 [N,K] ----------------
__global__ __launch_bounds__(256) void conv_t(const float* __restrict__ in,
                                              u16* __restrict__ out, int K, int N) {
  __shared__ float tile[64][65];
  int k0 = blockIdx.y << 6, n0 = blockIdx.x << 6;
  int t = threadIdx.x;
  int r = t >> 4, c4 = (t & 15) << 2;
  #pragma unroll
  for (int it = 0; it < 4; it++) {
    int row = r + it*16;
    f32x4 v = *(const f32x4*)(in + (size_t)(k0 + row)*N + n0 + c4);
    tile[row][c4+0] = v[0]; tile[row][c4+1] = v[1];
    tile[row][c4+2] = v[2]; tile[row][c4+3] = v[3];
  }
  __syncthreads();
  #pragma unroll
  for (int it = 0; it < 4; it++) {
    int nrow = r + it*16;
    u16x4 ov;
    #pragma unroll
    for (int e = 0; e < 4; e++) ov[e] = f2bf(tile[c4+e][nrow]);
    *(u16x4*)(out + (size_t)(n0 + nrow)*K + k0 + c4) = ov;
  }
}

// ---------------- RMSNorm: fp32 in [4096 rows x 4096] -> bf16 out ----------------
__global__ __launch_bounds__(256) void rmsnorm_kernel(const float* __restrict__ x,
                                                      const float* __restrict__ w,
                                                      u16* __restrict__ out) {
  int row = blockIdx.x, t = threadIdx.x;
  const float* xr = x + (size_t)row * 4096;
  f32x4 v[4];
  float ss = 0.f;
  #pragma unroll
  for (int i = 0; i < 4; i++) {
    v[i] = *(const f32x4*)(xr + (t + 256*i)*4);
    ss += v[i][0]*v[i][0] + v[i][1]*v[i][1] + v[i][2]*v[i][2] + v[i][3]*v[i][3];
  }
  #pragma unroll
  for (int d = 1; d < 64; d <<= 1) ss += __shfl_xor(ss, d, 64);
  __shared__ float ps[4];
  if ((t & 63) == 0) ps[t >> 6] = ss;
  __syncthreads();
  float scale = rsqrtf((ps[0]+ps[1]+ps[2]+ps[3]) * (1.f/4096.f) + 1e-6f);
  #pragma unroll
  for (int i = 0; i < 4; i++) {
    f32x4 wv = *(const f32x4*)(w + (t + 256*i)*4);
    u16x4 o;
    #pragma unroll
    for (int e = 0; e < 4; e++) o[e] = f2bf(v[i][e] * scale * wv[e]);
    *(u16x4*)(out + (size_t)row*4096 + (t + 256*i)*4) = o;
  }
}

// ---------------- RoPE in-place on q [tok,32*128] & k [tok,8*128]; q gets 1/sqrt(HD) ----------------
__global__ __launch_bounds__(256) void rope_kernel(u16* __restrict__ q, u16* __restrict__ k) {
  int tok = blockIdx.x;            // b*1024 + s ; position id == s
  int s = tok & 1023;
  __shared__ float cs[64], sn[64];
  int t = threadIdx.x;
  if (t < 64) {
    float inv = __expf(-(float)t * 0.14391156934f);  // ln(10000)/64
    float ang = (float)s * inv;
    cs[t] = cosf(ang); sn[t] = sinf(ang);
  }
  __syncthreads();
  const float qscale = 0.08838834764831845f;          // 1/sqrt(128)
  size_t qbase = (size_t)tok * 4096;
  #pragma unroll
  for (int it = 0; it < 8; it++) {
    int item = t + it*256; int h = item >> 6, j = item & 63;
    size_t i0 = qbase + h*128 + j;
    float x1 = bf2f(q[i0]), x2 = bf2f(q[i0+64]);
    float c = cs[j], si = sn[j];
    q[i0]    = f2bf((x1*c - x2*si) * qscale);
    q[i0+64] = f2bf((x2*c + x1*si) * qscale);
  }
  size_t kbase = (size_t)tok * 1024;
  #pragma unroll
  for (int it = 0; it < 2; it++) {
    int item = t + it*256; int h = item >> 6, j = item & 63;
    size_t i0 = kbase + h*128 + j;
    float x1 = bf2f(k[i0]), x2 = bf2f(k[i0+64]);
    float c = cs[j], si = sn[j];
    k[i0]    = f2bf(x1*c - x2*si);
    k[i0+64] = f2bf(x2*c + x1*si);
  }
}

// ---------------- V transpose per (b,kvh): [1024 x 128] -> vt [128 x 1024] ----------------
__global__ __launch_bounds__(256) void vtrans(const u16* __restrict__ v, u16* __restrict__ vt) {
  __shared__ u16 tile[32][33];
  int bh = blockIdx.z; int b = bh >> 3, kvh = bh & 7;
  int d0 = blockIdx.x << 5, s0 = blockIdx.y << 5;
  int tx = threadIdx.x, ty = threadIdx.y;   // (32,8)
  for (int r = ty; r < 32; r += 8)
    tile[r][tx] = v[(size_t)(b*1024 + s0 + r)*1024 + kvh*128 + d0 + tx];
  __syncthreads();
  for (int r = ty; r < 32; r += 8)
    vt[(size_t)((b*8 + kvh)*128 + d0 + r)*1024 + s0 + tx] = tile[tx][r];
}

// ---------------- 128-tile GEMM (kept for K/V projections: N=1024 too small for 256-tiles) ----------------
template<int EPI>
__global__ __launch_bounds__(256, 2) void gemm_bt(
    const u16* __restrict__ A, const u16* __restrict__ Bt,
    void* __restrict__ Cv, const float* __restrict__ resid,
    const u16* __restrict__ gate, int M, int N, int K) {
  __shared__ u16 As[128*64];
  __shared__ u16 Bs[128*64];
  int nwg = gridDim.x;
  int bid = (int)blockIdx.x;
  int cpx = nwg >> 3;
  int swz = (bid & 7) * cpx + (bid >> 3);
  int mt = M >> 7;
  int m0 = (swz % mt) << 7;
  int n0 = (swz / mt) << 7;
  int tid = threadIdx.x;
  int lane = tid & 63, wave = tid >> 6;
  int wm = wave >> 1, wn = wave & 1;

  f32x4 acc[4][4];
  f32x4 zero = {0.f, 0.f, 0.f, 0.f};
  #pragma unroll
  for (int i = 0; i < 4; i++)
    #pragma unroll
    for (int j = 0; j < 4; j++) acc[i][j] = zero;

  int arow[4], acolb[4];
  #pragma unroll
  for (int i = 0; i < 4; i++) {
    int c = i*256 + tid;
    arow[i]  = c >> 3;
    acolb[i] = ((c & 7) * 16) ^ ((arow[i] & 7) << 4);
  }

  int nsteps = K >> 6;
  for (int t = 0; t < nsteps; t++) {
    int k0 = t << 6;
    #pragma unroll
    for (int i = 0; i < 4; i++) {
      async16(As + i*2048 + wave*512, A  + (size_t)(m0 + arow[i])*K + k0 + (acolb[i] >> 1));
      async16(Bs + i*2048 + wave*512, Bt + (size_t)(n0 + arow[i])*K + k0 + (acolb[i] >> 1));
    }
    __syncthreads();
    #pragma unroll
    for (int ks = 0; ks < 2; ks++) {
      bf16x8 af[4], bfr[4];
      int c2 = (ks*32 + (lane >> 4)*8) * 2;
      #pragma unroll
      for (int mf = 0; mf < 4; mf++) {
        int r = wm*64 + mf*16 + (lane & 15);
        af[mf] = *(const bf16x8*)(As + r*64 + ((c2 ^ ((r & 7) << 4)) >> 1));
      }
      #pragma unroll
      for (int nf = 0; nf < 4; nf++) {
        int r = wn*64 + nf*16 + (lane & 15);
        bfr[nf] = *(const bf16x8*)(Bs + r*64 + ((c2 ^ ((r & 7) << 4)) >> 1));
      }
      #pragma unroll
      for (int mf = 0; mf < 4; mf++)
        #pragma unroll
        for (int nf = 0; nf < 4; nf++)
          acc[mf][nf] = __builtin_amdgcn_mfma_f32_16x16x32_bf16(af[mf], bfr[nf], acc[mf][nf], 0, 0, 0);
    }
    __syncthreads();
  }

  #pragma unroll
  for (int mf = 0; mf < 4; mf++)
    #pragma unroll
    for (int nf = 0; nf < 4; nf++)
      #pragma unroll
      for (int j = 0; j < 4; j++) {
        int rr = m0 + wm*64 + mf*16 + (lane >> 4)*4 + j;
        int cc = n0 + wn*64 + nf*16 + (lane & 15);
        size_t idx = (size_t)rr * N + cc;
        float v = acc[mf][nf][j];
        if constexpr (EPI == 0) {
          ((u16*)Cv)[idx] = f2bf(v);
        } else if constexpr (EPI == 1) {
          ((float*)Cv)[idx] = v + resid[idx];
        } else {
          float g = bf2f(gate[idx]);
          float sg = g / (1.f + __expf(-g));
          ((u16*)Cv)[idx] = f2bf(sg * v);
        }
      }
}

// ---------------- 256x256 GEMM with REGISTER READ-AHEAD (reads feed NEXT phase's MFMA) ----------------
// 512 thr = 8 waves (2M x 4N), wave out 128x64. BK=64. LDS 128 KiB = 2buf x (Aq0|Aq1|Bq0|Bq1) 16KB regions.
// Key mechanism (fix for 38% MfmaUtil serialization): each phase's ds_reads load the register
// subtile for the NEXT phase; MFMA uses data read one phase earlier; COUNTED lgkm waits (4/8/8/12,
// never 0 in steady state) leave this phase's reads in flight under the MFMA issue backpressure.
// Double-buffered register sets: afA (quadrant qm=0), afB (qm=1), b0, b1. One barrier per phase.
// Stage order per tile k (into buf^1, tile k+1): ph1:Aq0 ph2:Bq0 ph3:Bq1 ph4:Aq1; uniform vmcnt(4)
// after each stage-issue retires exactly the region whose ds_read follows the barrier (FIFO-verified).
// Region overwrite happens 6 phase-barriers after that region's last ds_read -> race-free.
#define SB0() __builtin_amdgcn_sched_barrier(0)
#define MFMAQ2(qm, qn, AF, BQ) do { \
  __builtin_amdgcn_s_setprio(1); \
  _Pragma("unroll") for (int mf_ = 0; mf_ < 4; mf_++) \
  _Pragma("unroll") for (int nf_ = 0; nf_ < 2; nf_++) \
  _Pragma("unroll") for (int ks_ = 0; ks_ < 2; ks_++) \
    acc[(qm)*4+mf_][(qn)*2+nf_] = __builtin_amdgcn_mfma_f32_16x16x32_bf16( \
        AF[mf_][ks_], BQ[nf_][ks_], acc[(qm)*4+mf_][(qn)*2+nf_], 0, 0, 0); \
  __builtin_amdgcn_s_setprio(0); } while (0)

template<int EPI>
__global__ __launch_bounds__(512, 2) void gemm256(
    const u16* __restrict__ A, const u16* __restrict__ Bt,
    void* __restrict__ Cv, const float* __restrict__ resid,
    const u16* __restrict__ gate, int M, int N, int K) {
  extern __shared__ u16 lds[];              // [2 bufs][A: 2 q-regions | B: 2 q-regions], 8192 u16/region
  int nwg = gridDim.x, bid = (int)blockIdx.x;
  int cpx = nwg >> 3;
  int swz = (bid & 7) * cpx + (bid >> 3);   // XCD-contiguous chunks (T1); all grids %8==0
  int mt = M >> 8;
  int m0 = (swz % mt) << 8;
  int n0 = (swz / mt) << 8;
  int tid = threadIdx.x, lane = tid & 63, wave = tid >> 6;
  int wm = wave >> 2, wn = wave & 3;

  f32x4 acc[8][4];
  f32x4 zero = {0.f, 0.f, 0.f, 0.f};
  #pragma unroll
  for (int i = 0; i < 8; i++)
    #pragma unroll
    for (int j = 0; j < 4; j++) acc[i][j] = zero;

  // staging: region chunk; global source pre-swizzled (rule #21)
  int sCol = ((lane & 7) ^ (lane >> 3)) << 3;                  // pre-swizzled global K-col (u16)
  int aRow = ((wave >> 2)*128) + (wave & 3)*16 + (lane >> 3);  // logical A row for region qm (+qm*64)
  int bRow = ((wave >> 1)*64)  + (wave & 1)*16 + (lane >> 3);  // logical B row for region qn (+qn*32)
  const u16* gA = A  + (size_t)(m0 + aRow) * K + sCol;
  const u16* gB = Bt + (size_t)(n0 + bRow) * K + sCol;
  size_t K8 = (size_t)8 * K, K32 = (size_t)32 * K, K64 = (size_t)64 * K;

  // fragment reads: within-region row = frag*16 + rA; stored chunk = logical ^ (row&7)
  int rA = lane & 15;
  int acol0 = (((lane >> 4)    ) ^ (rA & 7)) << 3;             // ks=0 (u16 units)
  int acol1 = (((lane >> 4) + 4) ^ (rA & 7)) << 3;             // ks=1

  bf16x8 afA[4][2], afB[4][2], b0[2][2], b1[2][2];

  auto stageAq = [&](int buf, int qm, int k0) {                // one 16KB region, 2 gloads/thread
    u16* d = lds + buf*32768 + qm*8192 + wave*1024;
    const u16* s = gA + (size_t)qm*K64 + k0;
    async16(d, s); async16(d + 512, s + K8);
  };
  auto stageBq = [&](int buf, int qn, int k0) {
    u16* d = lds + buf*32768 + 16384 + qn*8192 + wave*1024;
    const u16* s = gB + (size_t)qn*K32 + k0;
    async16(d, s); async16(d + 512, s + K8);
  };
  auto loadAq = [&](int buf, int qm, bf16x8 (&af)[4][2]) {     // 8 ds_read_b128
    const u16* base = lds + buf*32768 + qm*8192 + wm*4096 + rA*64;
    #pragma unroll
    for (int mf = 0; mf < 4; mf++) {
      af[mf][0] = *(const bf16x8*)(base + mf*1024 + acol0);
      af[mf][1] = *(const bf16x8*)(base + mf*1024 + acol1);
    }
  };
  auto loadBq = [&](int buf, int qn, bf16x8 (&bq)[2][2]) {     // 4 ds_read_b128
    const u16* base = lds + buf*32768 + 16384 + qn*8192 + wn*2048 + rA*64;
    #pragma unroll
    for (int nf = 0; nf < 2; nf++) {
      bq[nf][0] = *(const bf16x8*)(base + nf*1024 + acol0);
      bq[nf][1] = *(const bf16x8*)(base + nf*1024 + acol1);
    }
  };

  int nt = K >> 6;                           // nt >= 2 always here (K >= 4096)
  // prologue: stage whole tile 0, drain, then pre-read ph1's operands (afA, b0)
  stageAq(0, 0, 0); stageBq(0, 0, 0); stageBq(0, 1, 0); stageAq(0, 1, 0);
  SB0();
  asm volatile("s_waitcnt vmcnt(0)" ::: "memory");
  SB0();
  __builtin_amdgcn_s_barrier();
  SB0();
  loadAq(0, 0, afA); loadBq(0, 0, b0);

  for (int k = 0; k < nt; k++) {
    int buf = k & 1, nbuf = buf ^ 1;
    bool pre = (k + 1) < nt;
    int k1 = (k + 1) << 6;
    // ---- phase 1: MFMA Q(0,0)=afA,b0 ; read b1(k) ; stage Aq0(k+1)
    if (pre) { stageAq(nbuf, 0, k1); SB0();
               asm volatile("s_waitcnt vmcnt(4)" ::: "memory"); }  // retires Bq1(k)
    else     { asm volatile("s_waitcnt vmcnt(2)" ::: "memory"); }
    SB0();
    __builtin_amdgcn_s_barrier();
    SB0();
    loadBq(buf, 1, b1);
    asm volatile("s_waitcnt lgkmcnt(4)" ::: "memory");  // afA,b0 done; b1 in flight
    SB0();
    MFMAQ2(0, 0, afA, b0);
    // ---- phase 2: MFMA Q(0,1)=afA,b1 ; read afB(k) ; stage Bq0(k+1)
    if (pre) { stageBq(nbuf, 0, k1); SB0();
               asm volatile("s_waitcnt vmcnt(4)" ::: "memory"); }  // retires Aq1(k)
    else     { asm volatile("s_waitcnt vmcnt(0)" ::: "memory"); }
    SB0();
    __builtin_amdgcn_s_barrier();
    SB0();
    loadAq(buf, 1, afB);
    asm volatile("s_waitcnt lgkmcnt(8)" ::: "memory");  // b1 done; afB in flight
    SB0();
    MFMAQ2(0, 1, afA, b1);
    // ---- phase 3: MFMA Q(1,0)=afB,b0 ; read afA(k+1) ; stage Bq1(k+1)
    if (pre) { stageBq(nbuf, 1, k1); SB0();
               asm volatile("s_waitcnt vmcnt(4)" ::: "memory"); }  // retires Aq0(k+1)
    SB0();
    __builtin_amdgcn_s_barrier();
    SB0();
    if (pre) {
      loadAq(nbuf, 0, afA);
      asm volatile("s_waitcnt lgkmcnt(8)" ::: "memory");  // afB done; afA' in flight
    } else {
      asm volatile("s_waitcnt lgkmcnt(0)" ::: "memory");
    }
    SB0();
    MFMAQ2(1, 0, afB, b0);
    // ---- phase 4: MFMA Q(1,1)=afB,b1 ; read b0(k+1) ; stage Aq1(k+1)
    if (pre) { stageAq(nbuf, 1, k1); SB0();
               asm volatile("s_waitcnt vmcnt(4)" ::: "memory"); }  // retires Bq0(k+1)
    SB0();
    __builtin_amdgcn_s_barrier();
    SB0();
    if (pre) {
      loadBq(nbuf, 0, b0);
      asm volatile("s_waitcnt lgkmcnt(12)" ::: "memory"); // afB,b1 done; afA',b0' in flight
    } else {
      asm volatile("s_waitcnt lgkmcnt(0)" ::: "memory");
    }
    SB0();
    MFMAQ2(1, 1, afB, b1);
  }

  // C/D layout: col = lane&15, row = (lane>>4)*4 + j
  #pragma unroll
  for (int mf = 0; mf < 8; mf++)
    #pragma unroll
    for (int nf = 0; nf < 4; nf++)
      #pragma unroll
      for (int j = 0; j < 4; j++) {
        int rr = m0 + wm*128 + mf*16 + (lane >> 4)*4 + j;
        int cc = n0 + wn*64 + nf*16 + (lane & 15);
        size_t idx = (size_t)rr * N + cc;
        float v = acc[mf][nf][j];
        if constexpr (EPI == 0) {
          ((u16*)Cv)[idx] = f2bf(v);
        } else if constexpr (EPI == 1) {
          ((float*)Cv)[idx] = v + resid[idx];
        } else {
          float g = bf2f(gate[idx]);
          float sg = g / (1.f + __expf(-g));
          ((u16*)Cv)[idx] = f2bf(sg * v);
        }
      }
}

// ---------------- Flash attention, causal, GQA 4:1 ----------------
__global__ __launch_bounds__(256, 2) void attn_kernel(
    const u16* __restrict__ q, const u16* __restrict__ k,
    const u16* __restrict__ vt, u16* __restrict__ out) {
  __shared__ u16 Ks[64*128];
  __shared__ u16 Vs[128*64];
  __shared__ u16 Ps[4*16*64];
  int bid = blockIdx.x;
  int qt = bid & 15;
  int h  = (bid >> 4) & 31;
  int b  = bid >> 9;
  int kvh = h >> 2;
  int tid = threadIdx.x, lane = tid & 63, wave = tid >> 6;
  int q0 = qt << 6;

  bf16x8 qf[4];
  {
    const u16* qb_ = q + (size_t)(b*1024 + q0 + wave*16 + (lane & 15))*4096 + h*128 + (lane >> 4)*8;
    #pragma unroll
    for (int ks = 0; ks < 4; ks++) qf[ks] = *(const bf16x8*)(qb_ + ks*32);
  }
  f32x4 o[8];
  f32x4 zero = {0.f,0.f,0.f,0.f};
  #pragma unroll
  for (int i = 0; i < 8; i++) o[i] = zero;
  float m[4] = {-1e30f,-1e30f,-1e30f,-1e30f};
  float l[4] = {0.f,0.f,0.f,0.f};

  int kr[4], kc[4], vr[4], vc[4];
  #pragma unroll
  for (int i = 0; i < 4; i++) {
    int c = i*256 + tid;
    kr[i] = c >> 4; kc[i] = ((c & 15)*16) ^ ((kr[i] & 7) << 4);
    vr[i] = c >> 3; vc[i] = ((c & 7)*16)  ^ ((vr[i] & 7) << 4);
  }

  for (int t = 0; t <= qt; t++) {
    int kv0 = t << 6;
    #pragma unroll
    for (int i = 0; i < 4; i++) {
      async16(Ks + i*2048 + wave*512, k  + (size_t)(b*1024 + kv0 + kr[i])*1024 + kvh*128 + (kc[i] >> 1));
      async16(Vs + i*2048 + wave*512, vt + (size_t)((b*8 + kvh)*128 + vr[i])*1024 + kv0 + (vc[i] >> 1));
    }
    __syncthreads();

    f32x4 s[4];
    #pragma unroll
    for (int nf = 0; nf < 4; nf++) {
      s[nf] = zero;
      #pragma unroll
      for (int ks = 0; ks < 4; ks++) {
        int r = nf*16 + (lane & 15);
        int c2 = (ks*32 + (lane >> 4)*8)*2;
        bf16x8 kf = *(const bf16x8*)(Ks + r*128 + ((c2 ^ ((r & 7) << 4)) >> 1));
        s[nf] = __builtin_amdgcn_mfma_f32_16x16x32_bf16(qf[ks], kf, s[nf], 0, 0, 0);
      }
    }
    if (t == qt) {
      #pragma unroll
      for (int nf = 0; nf < 4; nf++)
        #pragma unroll
        for (int j = 0; j < 4; j++) {
          int cc = nf*16 + (lane & 15);
          int rr = wave*16 + (lane >> 4)*4 + j;
          if (cc > rr) s[nf][j] = -1e30f;
        }
    }
    #pragma unroll
    for (int j = 0; j < 4; j++) {
      float mx = fmaxf(fmaxf(s[0][j], s[1][j]), fmaxf(s[2][j], s[3][j]));
      #pragma unroll
      for (int d = 1; d < 16; d <<= 1) mx = fmaxf(mx, __shfl_xor(mx, d, 64));
      float mn = fmaxf(m[j], mx);
      float f = __expf(m[j] - mn);
      m[j] = mn;
      float ssum = 0.f;
      #pragma unroll
      for (int nf = 0; nf < 4; nf++) {
        float p = __expf(s[nf][j] - mn);
        s[nf][j] = p; ssum += p;
      }
      #pragma unroll
      for (int d = 1; d < 16; d <<= 1) ssum += __shfl_xor(ssum, d, 64);
      l[j] = l[j]*f + ssum;
      #pragma unroll
      for (int nf = 0; nf < 8; nf++) o[nf][j] *= f;
    }
    #pragma unroll
    for (int nf = 0; nf < 4; nf++)
      #pragma unroll
      for (int j = 0; j < 4; j++) {
        int rr = (lane >> 4)*4 + j;
        int cb = ((nf*16 + (lane & 15))*2) ^ ((rr & 7) << 4);
        Ps[wave*1024 + rr*64 + (cb >> 1)] = f2bf(s[nf][j]);
      }
    #pragma unroll
    for (int ks2 = 0; ks2 < 2; ks2++) {
      int mr = lane & 15;
      int c2 = (ks2*32 + (lane >> 4)*8)*2;
      bf16x8 pa = *(const bf16x8*)(Ps + wave*1024 + mr*64 + ((c2 ^ ((mr & 7) << 4)) >> 1));
      #pragma unroll
      for (int nf = 0; nf < 8; nf++) {
        int d = nf*16 + (lane & 15);
        bf16x8 vf = *(const bf16x8*)(Vs + d*64 + ((c2 ^ ((d & 7) << 4)) >> 1));
        o[nf] = __builtin_amdgcn_mfma_f32_16x16x32_bf16(pa, vf, o[nf], 0, 0, 0);
      }
    }
    __syncthreads();
  }

  float inv[4];
  #pragma unroll
  for (int j = 0; j < 4; j++) inv[j] = 1.f / l[j];
  u16* ob = out + (size_t)(b*1024 + q0 + wave*16)*4096 + h*128;
  #pragma unroll
  for (int nf = 0; nf < 8; nf++)
    #pragma unroll
    for (int j = 0; j < 4; j++) {
      int rr = (lane >> 4)*4 + j;
      int cc = nf*16 + (lane & 15);
      ob[(size_t)rr*4096 + cc] = f2bf(o[nf][j] * inv[j]);
    }
}

// ---------------- driver ----------------
extern "C" void kernel_launch(void* const* d_in, const int* in_sizes, int n_in,
                              void* d_out, int out_size, void* d_ws, size_t ws_size,
                              hipStream_t stream) {
  (void)in_sizes; (void)n_in; (void)out_size;
  const float* hidden = (const float*)d_in[0];
  const float* Wq  = (const float*)d_in[3];
  const float* Wk  = (const float*)d_in[4];
  const float* Wv  = (const float*)d_in[5];
  const float* Wo  = (const float*)d_in[6];
  const float* ln1 = (const float*)d_in[7];
  const float* ln2 = (const float*)d_in[8];
  const float* Wg  = (const float*)d_in[9];
  const float* Wu  = (const float*)d_in[10];
  const float* Wd  = (const float*)d_in[11];
  float* out = (float*)d_out;

  char* ws = (char*)d_ws;
  size_t off = 0;
  auto alloc = [&](size_t b) { char* p = ws + off; off += (b + 4095) & ~(size_t)4095; return p; };
  u16*  W1   = (u16*)alloc(90177536);
  u16*  h1   = (u16*)alloc(33554432);
  u16*  qb   = (u16*)alloc(33554432);
  u16*  kb   = (u16*)alloc(8388608);
  u16*  vb   = (u16*)alloc(8388608);
  u16*  vtb  = (u16*)alloc(8388608);
  float* hmid = (float*)alloc(67108864);
  u16*  gb   = (u16*)alloc(90177536);
  if (off > ws_size) return;

  u16* wqT = W1;
  u16* wkT = W1 + 16777216;
  u16* wvT = wkT + 4194304;

  hipFuncSetAttribute((const void*)gemm256<0>, hipFuncAttributeMaxDynamicSharedMemorySize, 131072);
  hipFuncSetAttribute((const void*)gemm256<1>, hipFuncAttributeMaxDynamicSharedMemorySize, 131072);
  hipFuncSetAttribute((const void*)gemm256<2>, hipFuncAttributeMaxDynamicSharedMemorySize, 131072);

  dim3 blk(256);
  // 1) QKV weights -> bf16 transposed
  conv_t<<<dim3(64, 64),  blk, 0, stream>>>(Wq, wqT, 4096, 4096);
  conv_t<<<dim3(16, 64),  blk, 0, stream>>>(Wk, wkT, 4096, 1024);
  conv_t<<<dim3(16, 64),  blk, 0, stream>>>(Wv, wvT, 4096, 1024);
  // 2) norm1
  rmsnorm_kernel<<<4096, blk, 0, stream>>>(hidden, ln1, h1);
  // 3) QKV projections (Q on 256-tile; K/V too narrow -> 128-tile)
  gemm256<0><<<256, 512, 131072, stream>>>(h1, wqT, qb, nullptr, nullptr, 4096, 4096, 4096);
  gemm_bt<0><<<256, blk, 0, stream>>>(h1, wkT, kb, nullptr, nullptr, 4096, 1024, 4096);
  gemm_bt<0><<<256, blk, 0, stream>>>(h1, wvT, vb, nullptr, nullptr, 4096, 1024, 4096);
  // 4) RoPE (q also gets 1/sqrt(HD))
  rope_kernel<<<4096, blk, 0, stream>>>(qb, kb);
  // 5) V transpose
  vtrans<<<dim3(4, 32, 32), dim3(32, 8), 0, stream>>>(vb, vtb);
  // 6) attention -> h1
  attn_kernel<<<2048, blk, 0, stream>>>(qb, kb, vtb, h1);
  // 7) Wo + residual -> hmid (fp32)
  conv_t<<<dim3(64, 64), blk, 0, stream>>>(Wo, W1, 4096, 4096);
  gemm256<1><<<256, 512, 131072, stream>>>(h1, W1, hmid, hidden, nullptr, 4096, 4096, 4096);
  // 8) norm2 -> qb
  rmsnorm_kernel<<<4096, blk, 0, stream>>>(hmid, ln2, qb);
  // 9) gate
  conv_t<<<dim3(172, 64), blk, 0, stream>>>(Wg, W1, 4096, 11008);
  gemm256<0><<<688, 512, 131072, stream>>>(qb, W1, gb, nullptr, nullptr, 4096, 11008, 4096);
  // 10) up, epilogue act = silu(gate)*up (in place over gb)
  conv_t<<<dim3(172, 64), blk, 0, stream>>>(Wu, W1, 4096, 11008);
  gemm256<2><<<688, 512, 131072, stream>>>(qb, W1, gb, nullptr, gb, 4096, 11008, 4096);
  // 11) down + residual -> d_out (fp32)
  conv_t<<<dim3(64, 172), blk, 0, stream>>>(Wd, W1, 11008, 4096);
  gemm256<1><<<256, 512, 131072, stream>>>(gb, W1, out, hmid, nullptr, 4096, 4096, 11008);
}

// Round 6
// 1697.624 us; speedup vs baseline: 1.0815x; 1.0716x over previous
//
#include <hip/hip_runtime.h>

#define DEVINL __device__ __forceinline__

typedef unsigned short u16;
typedef __attribute__((ext_vector_type(8))) short bf16x8;   // 8 bf16 = 4 VGPRs (MFMA A/B frag)
typedef __attribute__((ext_vector_type(4))) float f32x4;     // MFMA C/D frag
typedef __attribute__((ext_vector_type(4))) unsigned short u16x4;

// B=4, S=1024, HID=4096, NH=32, NKV=8, HD=128, FF=11008

DEVINL float bf2f(u16 u) { union { unsigned i; float f; } x; x.i = ((unsigned)u) << 16; return x.f; }
DEVINL u16 f2bf(float f) {                       // round-to-nearest-even
  union { float f; unsigned i; } x; x.f = f;
  unsigned r = x.i + 0x7fffu + ((x.i >> 16) & 1u);
  return (u16)(r >> 16);
}

DEVINL void async16(u16* lds, const u16* g) {
  __builtin_amdgcn_global_load_lds((const __attribute__((address_space(1))) unsigned*)g,
                                   (__attribute__((address_space(3))) unsigned*)lds, 16, 0, 0);
}

struct CJob { const float* in; u16* out; int K, N, ntiles; };

// one 64x64 convert+transpose tile; 256 participating threads t in [0,256); 2 block-wide syncs
DEVINL void conv_one(const float* __restrict__ in, u16* __restrict__ out,
                     int K, int N, int tile, int t, float (*tl)[65]) {
  int tn = N >> 6;
  int kt = tile / tn;
  int k0 = kt << 6, n0 = (tile - kt*tn) << 6;
  int r = t >> 4, c4 = (t & 15) << 2;
  #pragma unroll
  for (int it = 0; it < 4; it++) {
    int row = r + it*16;
    f32x4 v = *(const f32x4*)(in + (size_t)(k0 + row)*N + n0 + c4);
    tl[row][c4+0] = v[0]; tl[row][c4+1] = v[1];
    tl[row][c4+2] = v[2]; tl[row][c4+3] = v[3];
  }
  __syncthreads();
  #pragma unroll
  for (int it = 0; it < 4; it++) {
    int nrow = r + it*16;
    u16x4 ov;
    #pragma unroll
    for (int e = 0; e < 4; e++) ov[e] = f2bf(tl[c4+e][nrow]);
    *(u16x4*)(out + (size_t)(n0 + nrow)*K + k0 + c4) = ov;
  }
  __syncthreads();
}

// ---------------- standalone conv (QKV), grid-stride over 3 jobs ----------------
__global__ __launch_bounds__(256) void conv3(CJob j0, CJob j1, CJob j2) {
  __shared__ float tl[64][65];
  int ntot = j0.ntiles + j1.ntiles + j2.ntiles;
  for (int g = blockIdx.x; g < ntot; g += gridDim.x) {
    const float* in; u16* out; int K, N, tile;
    if (g < j0.ntiles)                 { in = j0.in; out = j0.out; K = j0.K; N = j0.N; tile = g; }
    else if (g < j0.ntiles + j1.ntiles){ in = j1.in; out = j1.out; K = j1.K; N = j1.N; tile = g - j0.ntiles; }
    else                               { in = j2.in; out = j2.out; K = j2.K; N = j2.N; tile = g - j0.ntiles - j1.ntiles; }
    conv_one(in, out, K, N, tile, threadIdx.x, tl);
  }
}

// ---------------- legacy conv (serial fallback path) ----------------
__global__ __launch_bounds__(256) void conv_t(const float* __restrict__ in,
                                              u16* __restrict__ out, int K, int N) {
  __shared__ float tl[64][65];
  int tile = blockIdx.y * gridDim.x + blockIdx.x;  // (y=kt, x=nt)
  conv_one(in, out, K, N, tile, threadIdx.x, tl);
}

// ---------------- RMSNorm: fp32 in [4096 rows x 4096] -> bf16 out ----------------
__global__ __launch_bounds__(256) void rmsnorm_kernel(const float* __restrict__ x,
                                                      const float* __restrict__ w,
                                                      u16* __restrict__ out) {
  int row = blockIdx.x, t = threadIdx.x;
  const float* xr = x + (size_t)row * 4096;
  f32x4 v[4];
  float ss = 0.f;
  #pragma unroll
  for (int i = 0; i < 4; i++) {
    v[i] = *(const f32x4*)(xr + (t + 256*i)*4);
    ss += v[i][0]*v[i][0] + v[i][1]*v[i][1] + v[i][2]*v[i][2] + v[i][3]*v[i][3];
  }
  #pragma unroll
  for (int d = 1; d < 64; d <<= 1) ss += __shfl_xor(ss, d, 64);
  __shared__ float ps[4];
  if ((t & 63) == 0) ps[t >> 6] = ss;
  __syncthreads();
  float scale = rsqrtf((ps[0]+ps[1]+ps[2]+ps[3]) * (1.f/4096.f) + 1e-6f);
  #pragma unroll
  for (int i = 0; i < 4; i++) {
    f32x4 wv = *(const f32x4*)(w + (t + 256*i)*4);
    u16x4 o;
    #pragma unroll
    for (int e = 0; e < 4; e++) o[e] = f2bf(v[i][e] * scale * wv[e]);
    *(u16x4*)(out + (size_t)row*4096 + (t + 256*i)*4) = o;
  }
}

// ---------------- RoPE in-place on q & k; q gets 1/sqrt(HD) ----------------
__global__ __launch_bounds__(256) void rope_kernel(u16* __restrict__ q, u16* __restrict__ k) {
  int tok = blockIdx.x;
  int s = tok & 1023;
  __shared__ float cs[64], sn[64];
  int t = threadIdx.x;
  if (t < 64) {
    float inv = __expf(-(float)t * 0.14391156934f);
    float ang = (float)s * inv;
    cs[t] = cosf(ang); sn[t] = sinf(ang);
  }
  __syncthreads();
  const float qscale = 0.08838834764831845f;
  size_t qbase = (size_t)tok * 4096;
  #pragma unroll
  for (int it = 0; it < 8; it++) {
    int item = t + it*256; int h = item >> 6, j = item & 63;
    size_t i0 = qbase + h*128 + j;
    float x1 = bf2f(q[i0]), x2 = bf2f(q[i0+64]);
    float c = cs[j], si = sn[j];
    q[i0]    = f2bf((x1*c - x2*si) * qscale);
    q[i0+64] = f2bf((x2*c + x1*si) * qscale);
  }
  size_t kbase = (size_t)tok * 1024;
  #pragma unroll
  for (int it = 0; it < 2; it++) {
    int item = t + it*256; int h = item >> 6, j = item & 63;
    size_t i0 = kbase + h*128 + j;
    float x1 = bf2f(k[i0]), x2 = bf2f(k[i0+64]);
    float c = cs[j], si = sn[j];
    k[i0]    = f2bf(x1*c - x2*si);
    k[i0+64] = f2bf(x2*c + x1*si);
  }
}

// ---------------- V transpose per (b,kvh): [1024 x 128] -> vt [128 x 1024] ----------------
__global__ __launch_bounds__(256) void vtrans(const u16* __restrict__ v, u16* __restrict__ vt) {
  __shared__ u16 tile[32][33];
  int bh = blockIdx.z; int b = bh >> 3, kvh = bh & 7;
  int d0 = blockIdx.x << 5, s0 = blockIdx.y << 5;
  int tx = threadIdx.x, ty = threadIdx.y;
  for (int r = ty; r < 32; r += 8)
    tile[r][tx] = v[(size_t)(b*1024 + s0 + r)*1024 + kvh*128 + d0 + tx];
  __syncthreads();
  for (int r = ty; r < 32; r += 8)
    vt[(size_t)((b*8 + kvh)*128 + d0 + r)*1024 + s0 + tx] = tile[tx][r];
}

// ---------------- 128-tile GEMM (K/V projections) ----------------
template<int EPI>
__global__ __launch_bounds__(256, 2) void gemm_bt(
    const u16* __restrict__ A, const u16* __restrict__ Bt,
    void* __restrict__ Cv, const float* __restrict__ resid,
    const u16* __restrict__ gate, int M, int N, int K) {
  __shared__ u16 As[128*64];
  __shared__ u16 Bs[128*64];
  int nwg = gridDim.x;
  int bid = (int)blockIdx.x;
  int cpx = nwg >> 3;
  int swz = (bid & 7) * cpx + (bid >> 3);
  int mt = M >> 7;
  int m0 = (swz % mt) << 7;
  int n0 = (swz / mt) << 7;
  int tid = threadIdx.x;
  int lane = tid & 63, wave = tid >> 6;
  int wm = wave >> 1, wn = wave & 1;

  f32x4 acc[4][4];
  f32x4 zero = {0.f, 0.f, 0.f, 0.f};
  #pragma unroll
  for (int i = 0; i < 4; i++)
    #pragma unroll
    for (int j = 0; j < 4; j++) acc[i][j] = zero;

  int arow[4], acolb[4];
  #pragma unroll
  for (int i = 0; i < 4; i++) {
    int c = i*256 + tid;
    arow[i]  = c >> 3;
    acolb[i] = ((c & 7) * 16) ^ ((arow[i] & 7) << 4);
  }

  int nsteps = K >> 6;
  for (int t = 0; t < nsteps; t++) {
    int k0 = t << 6;
    #pragma unroll
    for (int i = 0; i < 4; i++) {
      async16(As + i*2048 + wave*512, A  + (size_t)(m0 + arow[i])*K + k0 + (acolb[i] >> 1));
      async16(Bs + i*2048 + wave*512, Bt + (size_t)(n0 + arow[i])*K + k0 + (acolb[i] >> 1));
    }
    __syncthreads();
    #pragma unroll
    for (int ks = 0; ks < 2; ks++) {
      bf16x8 af[4], bfr[4];
      int c2 = (ks*32 + (lane >> 4)*8) * 2;
      #pragma unroll
      for (int mf = 0; mf < 4; mf++) {
        int r = wm*64 + mf*16 + (lane & 15);
        af[mf] = *(const bf16x8*)(As + r*64 + ((c2 ^ ((r & 7) << 4)) >> 1));
      }
      #pragma unroll
      for (int nf = 0; nf < 4; nf++) {
        int r = wn*64 + nf*16 + (lane & 15);
        bfr[nf] = *(const bf16x8*)(Bs + r*64 + ((c2 ^ ((r & 7) << 4)) >> 1));
      }
      #pragma unroll
      for (int mf = 0; mf < 4; mf++)
        #pragma unroll
        for (int nf = 0; nf < 4; nf++)
          acc[mf][nf] = __builtin_amdgcn_mfma_f32_16x16x32_bf16(af[mf], bfr[nf], acc[mf][nf], 0, 0, 0);
    }
    __syncthreads();
  }

  #pragma unroll
  for (int mf = 0; mf < 4; mf++)
    #pragma unroll
    for (int nf = 0; nf < 4; nf++)
      #pragma unroll
      for (int j = 0; j < 4; j++) {
        int rr = m0 + wm*64 + mf*16 + (lane >> 4)*4 + j;
        int cc = n0 + wn*64 + nf*16 + (lane & 15);
        size_t idx = (size_t)rr * N + cc;
        float v = acc[mf][nf][j];
        if constexpr (EPI == 0) {
          ((u16*)Cv)[idx] = f2bf(v);
        } else if constexpr (EPI == 1) {
          ((float*)Cv)[idx] = v + resid[idx];
        } else {
          float g = bf2f(gate[idx]);
          float sg = g / (1.f + __expf(-g));
          ((u16*)Cv)[idx] = f2bf(sg * v);
        }
      }
}

// ---------------- 256x256 GEMM: m201-faithful 8-phase / 2-K-tile unrolled, STATIC buffers ----------
// 512 thr = 8 waves (2M x 4N). BK=64. LDS 128 KiB = 2 bufs x (A: 2 regions | B: 2 regions) 16KB each.
// Iter covers tiles t(buf0), t+1(buf1). Phase = C-quadrant: {ds-reads (12/4/8/0), stage ONE half-tile,
// [lgkm(8) if 12 reads], barrier, lgkm(0), setprio(1), 16 MFMA, setprio(0), [vmcnt(6) at ph4/8], barrier}.
// Stage cadence: ph1:A1(t+1) ph2:A0(t+2) ph3:B0(t+2) ph4:B1(t+2)+vmcnt(6)[t+1 lands]
//                ph5:A1(t+2) ph6:A0(t+3) ph7:B0(t+3) ph8:B1(t+3)+vmcnt(6)[t+2 lands].
// Invariant: 6 loads (3 half-tiles) in flight at every phase-4/8 boundary; FIFO-verified.
#define SB0() __builtin_amdgcn_sched_barrier(0)
#define BAR() __builtin_amdgcn_s_barrier()
#define LGKM(n) do { SB0(); asm volatile("s_waitcnt lgkmcnt(" #n ")" ::: "memory"); SB0(); } while (0)
#define VMC(n)  do { SB0(); asm volatile("s_waitcnt vmcnt(" #n ")"  ::: "memory"); SB0(); } while (0)
#define MFMAQ(qm, qn, AF, BQ) do { \
  __builtin_amdgcn_s_setprio(1); \
  _Pragma("unroll") for (int mf_ = 0; mf_ < 4; mf_++) \
  _Pragma("unroll") for (int nf_ = 0; nf_ < 2; nf_++) \
  _Pragma("unroll") for (int ks_ = 0; ks_ < 2; ks_++) \
    acc[(qm)*4+mf_][(qn)*2+nf_] = __builtin_amdgcn_mfma_f32_16x16x32_bf16( \
        AF[mf_][ks_], BQ[nf_][ks_], acc[(qm)*4+mf_][(qn)*2+nf_], 0, 0, 0); \
  __builtin_amdgcn_s_setprio(0); } while (0)

template<int KC, int EPI>
__global__ __launch_bounds__(512, 2) void gemm256(
    const u16* __restrict__ A, const u16* __restrict__ Bt,
    void* __restrict__ Cv, const float* __restrict__ resid,
    const u16* __restrict__ gate, int M, int N, int G,
    const float* __restrict__ cvin, u16* __restrict__ cvout, int cvK, int cvN, int cvTiles) {
  extern __shared__ u16 lds[];
  int bid = (int)blockIdx.x;
  int tid = threadIdx.x;

  if (bid >= G) {                               // hosted conv blocks (fill ragged GEMM rounds)
    int cb = bid - G, CB = (int)gridDim.x - G;
    int h = tid >> 8, t = tid & 255;
    float (*tl)[65] = (float(*)[65])((char*)lds + h*16896);
    int pairs = cvTiles >> 1;                   // cvTiles even
    for (int p = cb; p < pairs; p += CB)
      conv_one(cvin, cvout, cvK, cvN, 2*p + h, t, tl);
    return;
  }

  int cpx = G >> 3;
  int swz = (bid & 7) * cpx + (bid >> 3);       // XCD swizzle (T1); G % 8 == 0
  int mt = M >> 8;
  int m0 = (swz % mt) << 8;
  int n0 = (swz / mt) << 8;
  int lane = tid & 63, wave = tid >> 6;
  int wm = wave >> 2, wn = wave & 3;

  f32x4 acc[8][4];
  f32x4 zero = {0.f, 0.f, 0.f, 0.f};
  #pragma unroll
  for (int i = 0; i < 8; i++)
    #pragma unroll
    for (int j = 0; j < 4; j++) acc[i][j] = zero;

  // staging addresses (global pre-swizzled, LDS linear — rule #21)
  int sCol = ((lane & 7) ^ (lane >> 3)) << 3;
  int aRow = (wave >> 2)*128 + (wave & 3)*16 + (lane >> 3);
  int bRow = (wave >> 1)*64  + (wave & 1)*16 + (lane >> 3);
  const u16* gA = A  + (size_t)(m0 + aRow) * KC + sCol;
  const u16* gB = Bt + (size_t)(n0 + bRow) * KC + sCol;
  constexpr size_t K8 = (size_t)8 * KC, K32 = (size_t)32 * KC, K64 = (size_t)64 * KC;

  // fragment read offsets: stored chunk = logical ^ (row&7)
  int rA = lane & 15;
  int acol0 = (((lane >> 4)    ) ^ (rA & 7)) << 3;
  int acol1 = (((lane >> 4) + 4) ^ (rA & 7)) << 3;

  bf16x8 afA[4][2], afB[4][2], b0[2][2], b1[2][2];

  auto stageAq = [&](int buf, int qm, int k0) {
    u16* d = lds + buf*32768 + qm*8192 + wave*1024;
    const u16* s = gA + (size_t)qm*K64 + k0;
    async16(d, s); async16(d + 512, s + K8);
  };
  auto stageBq = [&](int buf, int qn, int k0) {
    u16* d = lds + buf*32768 + 16384 + qn*8192 + wave*1024;
    const u16* s = gB + (size_t)qn*K32 + k0;
    async16(d, s); async16(d + 512, s + K8);
  };
  auto loadAq = [&](int buf, int qm, bf16x8 (&af)[4][2]) {     // 8 ds_read_b128
    const u16* base = lds + buf*32768 + qm*8192 + wm*4096 + rA*64;
    #pragma unroll
    for (int mf = 0; mf < 4; mf++) {
      af[mf][0] = *(const bf16x8*)(base + mf*1024 + acol0);
      af[mf][1] = *(const bf16x8*)(base + mf*1024 + acol1);
    }
  };
  auto loadBq = [&](int buf, int qn, bf16x8 (&bq)[2][2]) {     // 4 ds_read_b128
    const u16* base = lds + buf*32768 + 16384 + qn*8192 + wn*2048 + rA*64;
    #pragma unroll
    for (int nf = 0; nf < 2; nf++) {
      bq[nf][0] = *(const bf16x8*)(base + nf*1024 + acol0);
      bq[nf][1] = *(const bf16x8*)(base + nf*1024 + acol1);
    }
  };

  constexpr int nt = KC >> 6;                   // 64 or 172 (even, >= 4)
  constexpr int IT = nt/2 - 1;

  // prologue: tile0 (4 halves), vmcnt(4); tile1 (3 halves), vmcnt(6); barrier
  stageAq(0, 0, 0); stageBq(0, 0, 0); stageBq(0, 1, 0); stageAq(0, 1, 0);
  VMC(4);
  stageAq(1, 0, 64); stageBq(1, 0, 64); stageBq(1, 1, 64);
  VMC(6);
  BAR();

  #pragma unroll 1
  for (int it = 0; it < IT; it++) {
    int kc = it*128;
    // ph1 (buf0, Q00): 12 reads; stage A1(t+1)
    loadAq(0, 0, afA); loadBq(0, 0, b0); stageAq(1, 1, kc + 64);
    LGKM(8); BAR(); LGKM(0);
    MFMAQ(0, 0, afA, b0);
    SB0(); BAR();
    // ph2 (buf0, Q01): 4 reads; stage A0(t+2)
    loadBq(0, 1, b1); stageAq(0, 0, kc + 128);
    BAR(); LGKM(0);
    MFMAQ(0, 1, afA, b1);
    SB0(); BAR();
    // ph3 (buf0, Q10): 8 reads; stage B0(t+2)
    loadAq(0, 1, afB); stageBq(0, 0, kc + 128);
    BAR(); LGKM(0);
    MFMAQ(1, 0, afB, b0);
    SB0(); BAR();
    // ph4 (buf0, Q11): 0 reads; stage B1(t+2); vmcnt(6) lands tile t+1
    stageBq(0, 1, kc + 128);
    BAR();
    MFMAQ(1, 1, afB, b1);
    VMC(6); BAR();
    // ph5 (buf1, Q00): 12 reads; stage A1(t+2)
    loadAq(1, 0, afA); loadBq(1, 0, b0); stageAq(0, 1, kc + 128);
    LGKM(8); BAR(); LGKM(0);
    MFMAQ(0, 0, afA, b0);
    SB0(); BAR();
    // ph6 (buf1, Q01): 4 reads; stage A0(t+3)
    loadBq(1, 1, b1); stageAq(1, 0, kc + 192);
    BAR(); LGKM(0);
    MFMAQ(0, 1, afA, b1);
    SB0(); BAR();
    // ph7 (buf1, Q10): 8 reads; stage B0(t+3)
    loadAq(1, 1, afB); stageBq(1, 0, kc + 192);
    BAR(); LGKM(0);
    MFMAQ(1, 0, afB, b0);
    SB0(); BAR();
    // ph8 (buf1, Q11): 0 reads; stage B1(t+3); vmcnt(6) lands tile t+2
    stageBq(1, 1, kc + 192);
    BAR();
    MFMAQ(1, 1, afB, b1);
    VMC(6); BAR();
  }

  // epilogue: tiles nt-2 (buf0, landed) and nt-1 (buf1; A1 staged at e-ph1)
  {
    int kc = IT*128;
    loadAq(0, 0, afA); loadBq(0, 0, b0); stageAq(1, 1, kc + 64);
    LGKM(8); BAR(); LGKM(0);
    MFMAQ(0, 0, afA, b0);
    SB0(); BAR();
    loadBq(0, 1, b1);
    BAR(); LGKM(0);
    MFMAQ(0, 1, afA, b1);
    SB0(); BAR();
    loadAq(0, 1, afB);
    BAR(); LGKM(0);
    MFMAQ(1, 0, afB, b0);
    SB0(); BAR();
    MFMAQ(1, 1, afB, b1);
    VMC(0); BAR();
    // tile nt-1: pipelined drain, SB0-pinned read groups (counted lgkm = correctness here)
    loadAq(1, 0, afA); loadBq(1, 0, b0); SB0();
    loadBq(1, 1, b1); SB0();
    loadAq(1, 1, afB); SB0();
    LGKM(12); MFMAQ(0, 0, afA, b0);
    LGKM(8);  MFMAQ(0, 1, afA, b1);
    LGKM(0);  MFMAQ(1, 0, afB, b0);
    MFMAQ(1, 1, afB, b1);
  }

  // C/D layout: col = lane&15, row = (lane>>4)*4 + j
  #pragma unroll
  for (int mf = 0; mf < 8; mf++)
    #pragma unroll
    for (int nf = 0; nf < 4; nf++)
      #pragma unroll
      for (int j = 0; j < 4; j++) {
        int rr = m0 + wm*128 + mf*16 + (lane >> 4)*4 + j;
        int cc = n0 + wn*64 + nf*16 + (lane & 15);
        size_t idx = (size_t)rr * N + cc;
        float v = acc[mf][nf][j];
        if constexpr (EPI == 0) {
          ((u16*)Cv)[idx] = f2bf(v);
        } else if constexpr (EPI == 1) {
          ((float*)Cv)[idx] = v + resid[idx];
        } else {
          float g = bf2f(gate[idx]);
          float sg = g / (1.f + __expf(-g));
          ((u16*)Cv)[idx] = f2bf(sg * v);
        }
      }
}

// ---------------- Flash attention, causal, GQA 4:1 (+ hosted weight-conversion blocks) ----------------
__global__ __launch_bounds__(256, 2) void attn_kernel(
    const u16* __restrict__ q, const u16* __restrict__ k,
    const u16* __restrict__ vt, u16* __restrict__ out,
    CJob j0, CJob j1, CJob j2) {
  __shared__ __align__(16) u16 shm[20480];      // 40 KB: Ks 16K | Vs 16K | Ps 8K; conv reuses as fp32 tile
  u16* Ks = shm;
  u16* Vs = shm + 8192;
  u16* Ps = shm + 16384;
  int bid = blockIdx.x;

  if (bid >= 2048) {                            // hosted conv blocks
    int cb = bid - 2048, CB = (int)gridDim.x - 2048;
    float (*tl)[65] = (float(*)[65])shm;        // 16640 B <= 40960 B
    int ntot = j0.ntiles + j1.ntiles + j2.ntiles;
    for (int g = cb; g < ntot; g += CB) {
      const float* in; u16* outp; int K, N, tile;
      if (g < j0.ntiles)                  { in = j0.in; outp = j0.out; K = j0.K; N = j0.N; tile = g; }
      else if (g < j0.ntiles + j1.ntiles) { in = j1.in; outp = j1.out; K = j1.K; N = j1.N; tile = g - j0.ntiles; }
      else                                { in = j2.in; outp = j2.out; K = j2.K; N = j2.N; tile = g - j0.ntiles - j1.ntiles; }
      conv_one(in, outp, K, N, tile, threadIdx.x, tl);
    }
    return;
  }

  int qt = bid & 15;
  int h  = (bid >> 4) & 31;
  int b  = bid >> 9;
  int kvh = h >> 2;
  int tid = threadIdx.x, lane = tid & 63, wave = tid >> 6;
  int q0 = qt << 6;

  bf16x8 qf[4];
  {
    const u16* qb_ = q + (size_t)(b*1024 + q0 + wave*16 + (lane & 15))*4096 + h*128 + (lane >> 4)*8;
    #pragma unroll
    for (int ks = 0; ks < 4; ks++) qf[ks] = *(const bf16x8*)(qb_ + ks*32);
  }
  f32x4 o[8];
  f32x4 zero = {0.f,0.f,0.f,0.f};
  #pragma unroll
  for (int i = 0; i < 8; i++) o[i] = zero;
  float m[4] = {-1e30f,-1e30f,-1e30f,-1e30f};
  float l[4] = {0.f,0.f,0.f,0.f};

  int kr[4], kc[4], vr[4], vc[4];
  #pragma unroll
  for (int i = 0; i < 4; i++) {
    int c = i*256 + tid;
    kr[i] = c >> 4; kc[i] = ((c & 15)*16) ^ ((kr[i] & 7) << 4);
    vr[i] = c >> 3; vc[i] = ((c & 7)*16)  ^ ((vr[i] & 7) << 4);
  }

  for (int t = 0; t <= qt; t++) {
    int kv0 = t << 6;
    #pragma unroll
    for (int i = 0; i < 4; i++) {
      async16(Ks + i*2048 + wave*512, k  + (size_t)(b*1024 + kv0 + kr[i])*1024 + kvh*128 + (kc[i] >> 1));
      async16(Vs + i*2048 + wave*512, vt + (size_t)((b*8 + kvh)*128 + vr[i])*1024 + kv0 + (vc[i] >> 1));
    }
    __syncthreads();

    f32x4 s[4];
    #pragma unroll
    for (int nf = 0; nf < 4; nf++) {
      s[nf] = zero;
      #pragma unroll
      for (int ks = 0; ks < 4; ks++) {
        int r = nf*16 + (lane & 15);
        int c2 = (ks*32 + (lane >> 4)*8)*2;
        bf16x8 kf = *(const bf16x8*)(Ks + r*128 + ((c2 ^ ((r & 7) << 4)) >> 1));
        s[nf] = __builtin_amdgcn_mfma_f32_16x16x32_bf16(qf[ks], kf, s[nf], 0, 0, 0);
      }
    }
    if (t == qt) {
      #pragma unroll
      for (int nf = 0; nf < 4; nf++)
        #pragma unroll
        for (int j = 0; j < 4; j++) {
          int cc = nf*16 + (lane & 15);
          int rr = wave*16 + (lane >> 4)*4 + j;
          if (cc > rr) s[nf][j] = -1e30f;
        }
    }
    #pragma unroll
    for (int j = 0; j < 4; j++) {
      float mx = fmaxf(fmaxf(s[0][j], s[1][j]), fmaxf(s[2][j], s[3][j]));
      #pragma unroll
      for (int d = 1; d < 16; d <<= 1) mx = fmaxf(mx, __shfl_xor(mx, d, 64));
      float mn = fmaxf(m[j], mx);
      float f = __expf(m[j] - mn);
      m[j] = mn;
      float ssum = 0.f;
      #pragma unroll
      for (int nf = 0; nf < 4; nf++) {
        float p = __expf(s[nf][j] - mn);
        s[nf][j] = p; ssum += p;
      }
      #pragma unroll
      for (int d = 1; d < 16; d <<= 1) ssum += __shfl_xor(ssum, d, 64);
      l[j] = l[j]*f + ssum;
      #pragma unroll
      for (int nf = 0; nf < 8; nf++) o[nf][j] *= f;
    }
    #pragma unroll
    for (int nf = 0; nf < 4; nf++)
      #pragma unroll
      for (int j = 0; j < 4; j++) {
        int rr = (lane >> 4)*4 + j;
        int cb2 = ((nf*16 + (lane & 15))*2) ^ ((rr & 7) << 4);
        Ps[wave*1024 + rr*64 + (cb2 >> 1)] = f2bf(s[nf][j]);
      }
    #pragma unroll
    for (int ks2 = 0; ks2 < 2; ks2++) {
      int mr = lane & 15;
      int c2 = (ks2*32 + (lane >> 4)*8)*2;
      bf16x8 pa = *(const bf16x8*)(Ps + wave*1024 + mr*64 + ((c2 ^ ((mr & 7) << 4)) >> 1));
      #pragma unroll
      for (int nf = 0; nf < 8; nf++) {
        int d = nf*16 + (lane & 15);
        bf16x8 vf = *(const bf16x8*)(Vs + d*64 + ((c2 ^ ((d & 7) << 4)) >> 1));
        o[nf] = __builtin_amdgcn_mfma_f32_16x16x32_bf16(pa, vf, o[nf], 0, 0, 0);
      }
    }
    __syncthreads();
  }

  float inv[4];
  #pragma unroll
  for (int j = 0; j < 4; j++) inv[j] = 1.f / l[j];
  u16* ob = out + (size_t)(b*1024 + q0 + wave*16)*4096 + h*128;
  #pragma unroll
  for (int nf = 0; nf < 8; nf++)
    #pragma unroll
    for (int j = 0; j < 4; j++) {
      int rr = (lane >> 4)*4 + j;
      int cc = nf*16 + (lane & 15);
      ob[(size_t)rr*4096 + cc] = f2bf(o[nf][j] * inv[j]);
    }
}

// ---------------- driver ----------------
extern "C" void kernel_launch(void* const* d_in, const int* in_sizes, int n_in,
                              void* d_out, int out_size, void* d_ws, size_t ws_size,
                              hipStream_t stream) {
  (void)in_sizes; (void)n_in; (void)out_size;
  const float* hidden = (const float*)d_in[0];
  const float* Wq  = (const float*)d_in[3];
  const float* Wk  = (const float*)d_in[4];
  const float* Wv  = (const float*)d_in[5];
  const float* Wo  = (const float*)d_in[6];
  const float* ln1 = (const float*)d_in[7];
  const float* ln2 = (const float*)d_in[8];
  const float* Wg  = (const float*)d_in[9];
  const float* Wu  = (const float*)d_in[10];
  const float* Wd  = (const float*)d_in[11];
  float* out = (float*)d_out;

  hipFuncSetAttribute((const void*)gemm256<4096,0>,  hipFuncAttributeMaxDynamicSharedMemorySize, 131072);
  hipFuncSetAttribute((const void*)gemm256<4096,1>,  hipFuncAttributeMaxDynamicSharedMemorySize, 131072);
  hipFuncSetAttribute((const void*)gemm256<4096,2>,  hipFuncAttributeMaxDynamicSharedMemorySize, 131072);
  hipFuncSetAttribute((const void*)gemm256<11008,1>, hipFuncAttributeMaxDynamicSharedMemorySize, 131072);

  char* ws = (char*)d_ws;
  size_t off = 0;
  auto alloc = [&](size_t b) { char* p = ws + off; off += (b + 4095) & ~(size_t)4095; return p; };

  // fused layout
  u16*  wqkvT = (u16*)alloc(50331648);   // [6144][4096] bf16: wq | wk | wv
  u16*  woT   = (u16*)alloc(33554432);
  u16*  wgT   = (u16*)alloc(90177536);   // reused for Wd after gate-GEMM
  u16*  wuT   = (u16*)alloc(90177536);
  u16*  h1    = (u16*)alloc(33554432);
  u16*  qb    = (u16*)alloc(33554432);
  u16*  kb    = (u16*)alloc(8388608);
  u16*  vb    = (u16*)alloc(8388608);
  u16*  vtb   = (u16*)alloc(8388608);
  float* hmid = (float*)alloc(67108864);
  u16*  gb    = (u16*)alloc(90177536);
  bool fused = off <= ws_size;

  dim3 blk(256);
  if (fused) {
    u16* wqT = wqkvT;
    u16* wkT = wqkvT + 16777216;
    u16* wvT = wkT + 4194304;
    u16* wdT = wgT;
    CJob Jq{Wq, wqT, 4096, 4096, 4096}, Jk{Wk, wkT, 4096, 1024, 1024}, Jv{Wv, wvT, 4096, 1024, 1024};
    CJob Jo{Wo, woT, 4096, 4096, 4096}, Jg{Wg, wgT, 4096, 11008, 11008}, Ju{Wu, wuT, 4096, 11008, 11008};

    conv3<<<2048, blk, 0, stream>>>(Jq, Jk, Jv);
    rmsnorm_kernel<<<4096, blk, 0, stream>>>(hidden, ln1, h1);
    gemm256<4096,0><<<256, 512, 131072, stream>>>(h1, wqT, qb, nullptr, nullptr, 4096, 4096, 256,
                                                  nullptr, nullptr, 0, 0, 0);
    gemm_bt<0><<<256, blk, 0, stream>>>(h1, wkT, kb, nullptr, nullptr, 4096, 1024, 4096);
    gemm_bt<0><<<256, blk, 0, stream>>>(h1, wvT, vb, nullptr, nullptr, 4096, 1024, 4096);
    rope_kernel<<<4096, blk, 0, stream>>>(qb, kb);
    vtrans<<<dim3(4, 32, 32), dim3(32, 8), 0, stream>>>(vb, vtb);
    // attention + hosted conversions of Wo, Wg, Wu
    attn_kernel<<<2048 + 1024, blk, 0, stream>>>(qb, kb, vtb, h1, Jo, Jg, Ju);
    gemm256<4096,1><<<256, 512, 131072, stream>>>(h1, woT, hmid, hidden, nullptr, 4096, 4096, 256,
                                                  nullptr, nullptr, 0, 0, 0);
    rmsnorm_kernel<<<4096, blk, 0, stream>>>(hmid, ln2, qb);
    gemm256<4096,0><<<688, 512, 131072, stream>>>(qb, wgT, gb, nullptr, nullptr, 4096, 11008, 688,
                                                  nullptr, nullptr, 0, 0, 0);
    // up-GEMM + hosted conversion of Wd (into wgT slot; gate-GEMM already done)
    gemm256<4096,2><<<688 + 344, 512, 131072, stream>>>(qb, wuT, gb, nullptr, gb, 4096, 11008, 688,
                                                        Wd, wdT, 11008, 4096, 11008);
    gemm256<11008,1><<<256, 512, 131072, stream>>>(gb, wdT, out, hmid, nullptr, 4096, 4096, 256,
                                                   nullptr, nullptr, 0, 0, 0);
  } else {
    // serial fallback (smaller footprint): one big W slot reused
    off = 0;
    u16*  W1   = (u16*)alloc(90177536);
    u16*  h1s  = (u16*)alloc(33554432);
    u16*  qbs  = (u16*)alloc(33554432);
    u16*  kbs  = (u16*)alloc(8388608);
    u16*  vbs  = (u16*)alloc(8388608);
    u16*  vtbs = (u16*)alloc(8388608);
    float* hmids = (float*)alloc(67108864);
    u16*  gbs  = (u16*)alloc(90177536);
    if (off > ws_size) return;
    u16* wqT = W1;
    u16* wkT = W1 + 16777216;
    u16* wvT = wkT + 4194304;
    conv_t<<<dim3(64, 64),  blk, 0, stream>>>(Wq, wqT, 4096, 4096);
    conv_t<<<dim3(16, 64),  blk, 0, stream>>>(Wk, wkT, 4096, 1024);
    conv_t<<<dim3(16, 64),  blk, 0, stream>>>(Wv, wvT, 4096, 1024);
    rmsnorm_kernel<<<4096, blk, 0, stream>>>(hidden, ln1, h1s);
    gemm256<4096,0><<<256, 512, 131072, stream>>>(h1s, wqT, qbs, nullptr, nullptr, 4096, 4096, 256,
                                                  nullptr, nullptr, 0, 0, 0);
    gemm_bt<0><<<256, blk, 0, stream>>>(h1s, wkT, kbs, nullptr, nullptr, 4096, 1024, 4096);
    gemm_bt<0><<<256, blk, 0, stream>>>(h1s, wvT, vbs, nullptr, nullptr, 4096, 1024, 4096);
    rope_kernel<<<4096, blk, 0, stream>>>(qbs, kbs);
    vtrans<<<dim3(4, 32, 32), dim3(32, 8), 0, stream>>>(vbs, vtbs);
    CJob J0{nullptr, nullptr, 0, 64, 0};
    attn_kernel<<<2048, blk, 0, stream>>>(qbs, kbs, vtbs, h1s, J0, J0, J0);
    conv_t<<<dim3(64, 64), blk, 0, stream>>>(Wo, W1, 4096, 4096);
    gemm256<4096,1><<<256, 512, 131072, stream>>>(h1s, W1, hmids, hidden, nullptr, 4096, 4096, 256,
                                                  nullptr, nullptr, 0, 0, 0);
    rmsnorm_kernel<<<4096, blk, 0, stream>>>(hmids, ln2, qbs);
    conv_t<<<dim3(172, 64), blk, 0, stream>>>(Wg, W1, 4096, 11008);
    gemm256<4096,0><<<688, 512, 131072, stream>>>(qbs, W1, gbs, nullptr, nullptr, 4096, 11008, 688,
                                                  nullptr, nullptr, 0, 0, 0);
    conv_t<<<dim3(172, 64), blk, 0, stream>>>(Wu, W1, 4096, 11008);
    gemm256<4096,2><<<688, 512, 131072, stream>>>(qbs, W1, gbs, nullptr, gbs, 4096, 11008, 688,
                                                  nullptr, nullptr, 0, 0, 0);
    conv_t<<<dim3(64, 172), blk, 0, stream>>>(Wd, W1, 11008, 4096);
    gemm256<11008,1><<<256, 512, 131072, stream>>>(gbs, W1, out, hmids, nullptr, 4096, 4096, 256,
                                                   nullptr, nullptr, 0, 0, 0);
  }
}

// Round 7
// 1665.283 us; speedup vs baseline: 1.1025x; 1.0194x over previous
//
#include <hip/hip_runtime.h>

#define DEVINL __device__ __forceinline__

typedef unsigned short u16;
typedef __attribute__((ext_vector_type(8))) short bf16x8;   // 8 bf16 = 4 VGPRs (MFMA A/B frag)
typedef __attribute__((ext_vector_type(4))) float f32x4;     // MFMA C/D frag
typedef __attribute__((ext_vector_type(4))) unsigned short u16x4;

// B=4, S=1024, HID=4096, NH=32, NKV=8, HD=128, FF=11008

DEVINL float bf2f(u16 u) { union { unsigned i; float f; } x; x.i = ((unsigned)u) << 16; return x.f; }
DEVINL u16 f2bf(float f) {                       // round-to-nearest-even
  union { float f; unsigned i; } x; x.f = f;
  unsigned r = x.i + 0x7fffu + ((x.i >> 16) & 1u);
  return (u16)(r >> 16);
}

DEVINL void async16(u16* lds, const u16* g) {
  __builtin_amdgcn_global_load_lds((const __attribute__((address_space(1))) unsigned*)g,
                                   (__attribute__((address_space(3))) unsigned*)lds, 16, 0, 0);
}

struct CJob { const float* in; u16* out; int K, N, ntiles; };

// one 64x64 convert+transpose tile; 256 participating threads t in [0,256); 2 block-wide syncs
DEVINL void conv_one(const float* __restrict__ in, u16* __restrict__ out,
                     int K, int N, int tile, int t, float (*tl)[65]) {
  int tn = N >> 6;
  int kt = tile / tn;
  int k0 = kt << 6, n0 = (tile - kt*tn) << 6;
  int r = t >> 4, c4 = (t & 15) << 2;
  #pragma unroll
  for (int it = 0; it < 4; it++) {
    int row = r + it*16;
    f32x4 v = *(const f32x4*)(in + (size_t)(k0 + row)*N + n0 + c4);
    tl[row][c4+0] = v[0]; tl[row][c4+1] = v[1];
    tl[row][c4+2] = v[2]; tl[row][c4+3] = v[3];
  }
  __syncthreads();
  #pragma unroll
  for (int it = 0; it < 4; it++) {
    int nrow = r + it*16;
    u16x4 ov;
    #pragma unroll
    for (int e = 0; e < 4; e++) ov[e] = f2bf(tl[c4+e][nrow]);
    *(u16x4*)(out + (size_t)(n0 + nrow)*K + k0 + c4) = ov;
  }
  __syncthreads();
}

// ---------------- standalone conv (QKV), grid-stride over 3 jobs ----------------
__global__ __launch_bounds__(256) void conv3(CJob j0, CJob j1, CJob j2) {
  __shared__ float tl[64][65];
  int ntot = j0.ntiles + j1.ntiles + j2.ntiles;
  for (int g = blockIdx.x; g < ntot; g += gridDim.x) {
    const float* in; u16* out; int K, N, tile;
    if (g < j0.ntiles)                 { in = j0.in; out = j0.out; K = j0.K; N = j0.N; tile = g; }
    else if (g < j0.ntiles + j1.ntiles){ in = j1.in; out = j1.out; K = j1.K; N = j1.N; tile = g - j0.ntiles; }
    else                               { in = j2.in; out = j2.out; K = j2.K; N = j2.N; tile = g - j0.ntiles - j1.ntiles; }
    conv_one(in, out, K, N, tile, threadIdx.x, tl);
  }
}

// ---------------- legacy conv (serial fallback path) ----------------
__global__ __launch_bounds__(256) void conv_t(const float* __restrict__ in,
                                              u16* __restrict__ out, int K, int N) {
  __shared__ float tl[64][65];
  int tile = blockIdx.y * gridDim.x + blockIdx.x;  // (y=kt, x=nt)
  conv_one(in, out, K, N, tile, threadIdx.x, tl);
}

// ---------------- RMSNorm: fp32 in [4096 rows x 4096] -> bf16 out ----------------
__global__ __launch_bounds__(256) void rmsnorm_kernel(const float* __restrict__ x,
                                                      const float* __restrict__ w,
                                                      u16* __restrict__ out) {
  int row = blockIdx.x, t = threadIdx.x;
  const float* xr = x + (size_t)row * 4096;
  f32x4 v[4];
  float ss = 0.f;
  #pragma unroll
  for (int i = 0; i < 4; i++) {
    v[i] = *(const f32x4*)(xr + (t + 256*i)*4);
    ss += v[i][0]*v[i][0] + v[i][1]*v[i][1] + v[i][2]*v[i][2] + v[i][3]*v[i][3];
  }
  #pragma unroll
  for (int d = 1; d < 64; d <<= 1) ss += __shfl_xor(ss, d, 64);
  __shared__ float ps[4];
  if ((t & 63) == 0) ps[t >> 6] = ss;
  __syncthreads();
  float scale = rsqrtf((ps[0]+ps[1]+ps[2]+ps[3]) * (1.f/4096.f) + 1e-6f);
  #pragma unroll
  for (int i = 0; i < 4; i++) {
    f32x4 wv = *(const f32x4*)(w + (t + 256*i)*4);
    u16x4 o;
    #pragma unroll
    for (int e = 0; e < 4; e++) o[e] = f2bf(v[i][e] * scale * wv[e]);
    *(u16x4*)(out + (size_t)row*4096 + (t + 256*i)*4) = o;
  }
}

// ---------------- RoPE in-place on q [tok,4096] & k [tok, kstr]; q gets 1/sqrt(HD) ----------------
__global__ __launch_bounds__(256) void rope_kernel(u16* __restrict__ q, u16* __restrict__ k, int kstr) {
  int tok = blockIdx.x;
  int s = tok & 1023;
  __shared__ float cs[64], sn[64];
  int t = threadIdx.x;
  if (t < 64) {
    float inv = __expf(-(float)t * 0.14391156934f);
    float ang = (float)s * inv;
    cs[t] = cosf(ang); sn[t] = sinf(ang);
  }
  __syncthreads();
  const float qscale = 0.08838834764831845f;
  size_t qbase = (size_t)tok * 4096;
  #pragma unroll
  for (int it = 0; it < 8; it++) {
    int item = t + it*256; int h = item >> 6, j = item & 63;
    size_t i0 = qbase + h*128 + j;
    float x1 = bf2f(q[i0]), x2 = bf2f(q[i0+64]);
    float c = cs[j], si = sn[j];
    q[i0]    = f2bf((x1*c - x2*si) * qscale);
    q[i0+64] = f2bf((x2*c + x1*si) * qscale);
  }
  size_t kbase = (size_t)tok * kstr;
  #pragma unroll
  for (int it = 0; it < 2; it++) {
    int item = t + it*256; int h = item >> 6, j = item & 63;
    size_t i0 = kbase + h*128 + j;
    float x1 = bf2f(k[i0]), x2 = bf2f(k[i0+64]);
    float c = cs[j], si = sn[j];
    k[i0]    = f2bf(x1*c - x2*si);
    k[i0+64] = f2bf(x2*c + x1*si);
  }
}

// ---------------- V transpose per (b,kvh): [1024 x 128] (stride vstr) -> vt [128 x 1024] ----------------
__global__ __launch_bounds__(256) void vtrans(const u16* __restrict__ v, u16* __restrict__ vt, int vstr) {
  __shared__ u16 tile[32][33];
  int bh = blockIdx.z; int b = bh >> 3, kvh = bh & 7;
  int d0 = blockIdx.x << 5, s0 = blockIdx.y << 5;
  int tx = threadIdx.x, ty = threadIdx.y;
  for (int r = ty; r < 32; r += 8)
    tile[r][tx] = v[(size_t)(b*1024 + s0 + r)*vstr + kvh*128 + d0 + tx];
  __syncthreads();
  for (int r = ty; r < 32; r += 8)
    vt[(size_t)((b*8 + kvh)*128 + d0 + r)*1024 + s0 + tx] = tile[tx][r];
}

// ---------------- 128-tile GEMM (merged K+V projection) ----------------
template<int EPI>
__global__ __launch_bounds__(256, 2) void gemm_bt(
    const u16* __restrict__ A, const u16* __restrict__ Bt,
    void* __restrict__ Cv, const float* __restrict__ resid,
    const u16* __restrict__ gate, int M, int N, int K) {
  __shared__ u16 As[128*64];
  __shared__ u16 Bs[128*64];
  int nwg = gridDim.x;
  int bid = (int)blockIdx.x;
  int cpx = nwg >> 3;
  int swz = (bid & 7) * cpx + (bid >> 3);
  int mt = M >> 7;
  int m0 = (swz % mt) << 7;
  int n0 = (swz / mt) << 7;
  int tid = threadIdx.x;
  int lane = tid & 63, wave = tid >> 6;
  int wm = wave >> 1, wn = wave & 1;

  f32x4 acc[4][4];
  f32x4 zero = {0.f, 0.f, 0.f, 0.f};
  #pragma unroll
  for (int i = 0; i < 4; i++)
    #pragma unroll
    for (int j = 0; j < 4; j++) acc[i][j] = zero;

  int arow[4], acolb[4];
  #pragma unroll
  for (int i = 0; i < 4; i++) {
    int c = i*256 + tid;
    arow[i]  = c >> 3;
    acolb[i] = ((c & 7) * 16) ^ ((arow[i] & 7) << 4);
  }

  int nsteps = K >> 6;
  for (int t = 0; t < nsteps; t++) {
    int k0 = t << 6;
    #pragma unroll
    for (int i = 0; i < 4; i++) {
      async16(As + i*2048 + wave*512, A  + (size_t)(m0 + arow[i])*K + k0 + (acolb[i] >> 1));
      async16(Bs + i*2048 + wave*512, Bt + (size_t)(n0 + arow[i])*K + k0 + (acolb[i] >> 1));
    }
    __syncthreads();
    #pragma unroll
    for (int ks = 0; ks < 2; ks++) {
      bf16x8 af[4], bfr[4];
      int c2 = (ks*32 + (lane >> 4)*8) * 2;
      #pragma unroll
      for (int mf = 0; mf < 4; mf++) {
        int r = wm*64 + mf*16 + (lane & 15);
        af[mf] = *(const bf16x8*)(As + r*64 + ((c2 ^ ((r & 7) << 4)) >> 1));
      }
      #pragma unroll
      for (int nf = 0; nf < 4; nf++) {
        int r = wn*64 + nf*16 + (lane & 15);
        bfr[nf] = *(const bf16x8*)(Bs + r*64 + ((c2 ^ ((r & 7) << 4)) >> 1));
      }
      #pragma unroll
      for (int mf = 0; mf < 4; mf++)
        #pragma unroll
        for (int nf = 0; nf < 4; nf++)
          acc[mf][nf] = __builtin_amdgcn_mfma_f32_16x16x32_bf16(af[mf], bfr[nf], acc[mf][nf], 0, 0, 0);
    }
    __syncthreads();
  }

  #pragma unroll
  for (int mf = 0; mf < 4; mf++)
    #pragma unroll
    for (int nf = 0; nf < 4; nf++)
      #pragma unroll
      for (int j = 0; j < 4; j++) {
        int rr = m0 + wm*64 + mf*16 + (lane >> 4)*4 + j;
        int cc = n0 + wn*64 + nf*16 + (lane & 15);
        size_t idx = (size_t)rr * N + cc;
        float v = acc[mf][nf][j];
        if constexpr (EPI == 0) {
          ((u16*)Cv)[idx] = f2bf(v);
        } else if constexpr (EPI == 1) {
          ((float*)Cv)[idx] = v + resid[idx];
        } else {
          float g = bf2f(gate[idx]);
          float sg = g / (1.f + __expf(-g));
          ((u16*)Cv)[idx] = f2bf(sg * v);
        }
      }
}

// ---------------- 256x256 GEMM: 8-phase / 2-K-tile unrolled, STATIC buffers ----------
#define SB0() __builtin_amdgcn_sched_barrier(0)
#define BAR() __builtin_amdgcn_s_barrier()
#define LGKM(n) do { SB0(); asm volatile("s_waitcnt lgkmcnt(" #n ")" ::: "memory"); SB0(); } while (0)
#define VMC(n)  do { SB0(); asm volatile("s_waitcnt vmcnt(" #n ")"  ::: "memory"); SB0(); } while (0)
#define MFMAQ(qm, qn, AF, BQ) do { \
  __builtin_amdgcn_s_setprio(1); \
  _Pragma("unroll") for (int mf_ = 0; mf_ < 4; mf_++) \
  _Pragma("unroll") for (int nf_ = 0; nf_ < 2; nf_++) \
  _Pragma("unroll") for (int ks_ = 0; ks_ < 2; ks_++) \
    acc[(qm)*4+mf_][(qn)*2+nf_] = __builtin_amdgcn_mfma_f32_16x16x32_bf16( \
        AF[mf_][ks_], BQ[nf_][ks_], acc[(qm)*4+mf_][(qn)*2+nf_], 0, 0, 0); \
  __builtin_amdgcn_s_setprio(0); } while (0)

template<int KC, int EPI>
__global__ __launch_bounds__(512, 2) void gemm256(
    const u16* __restrict__ A, const u16* __restrict__ Bt,
    void* __restrict__ Cv, const float* __restrict__ resid,
    const u16* __restrict__ gate, int M, int N, int G,
    const float* __restrict__ cvin, u16* __restrict__ cvout, int cvK, int cvN, int cvTiles) {
  extern __shared__ u16 lds[];
  int bid = (int)blockIdx.x;
  int tid = threadIdx.x;

  if (bid >= G) {                               // hosted conv blocks
    int cb = bid - G, CB = (int)gridDim.x - G;
    int h = tid >> 8, t = tid & 255;
    float (*tl)[65] = (float(*)[65])((char*)lds + h*16896);
    int pairs = cvTiles >> 1;
    for (int p = cb; p < pairs; p += CB)
      conv_one(cvin, cvout, cvK, cvN, 2*p + h, t, tl);
    return;
  }

  int cpx = G >> 3;
  int swz = (bid & 7) * cpx + (bid >> 3);       // XCD swizzle (T1); G % 8 == 0
  int mt = M >> 8;
  int m0 = (swz % mt) << 8;
  int n0 = (swz / mt) << 8;
  int lane = tid & 63, wave = tid >> 6;
  int wm = wave >> 2, wn = wave & 3;

  f32x4 acc[8][4];
  f32x4 zero = {0.f, 0.f, 0.f, 0.f};
  #pragma unroll
  for (int i = 0; i < 8; i++)
    #pragma unroll
    for (int j = 0; j < 4; j++) acc[i][j] = zero;

  int sCol = ((lane & 7) ^ (lane >> 3)) << 3;
  int aRow = (wave >> 2)*128 + (wave & 3)*16 + (lane >> 3);
  int bRow = (wave >> 1)*64  + (wave & 1)*16 + (lane >> 3);
  const u16* gA = A  + (size_t)(m0 + aRow) * KC + sCol;
  const u16* gB = Bt + (size_t)(n0 + bRow) * KC + sCol;
  constexpr size_t K8 = (size_t)8 * KC, K32 = (size_t)32 * KC, K64 = (size_t)64 * KC;

  int rA = lane & 15;
  int acol0 = (((lane >> 4)    ) ^ (rA & 7)) << 3;
  int acol1 = (((lane >> 4) + 4) ^ (rA & 7)) << 3;

  bf16x8 afA[4][2], afB[4][2], b0[2][2], b1[2][2];

  auto stageAq = [&](int buf, int qm, int k0) {
    u16* d = lds + buf*32768 + qm*8192 + wave*1024;
    const u16* s = gA + (size_t)qm*K64 + k0;
    async16(d, s); async16(d + 512, s + K8);
  };
  auto stageBq = [&](int buf, int qn, int k0) {
    u16* d = lds + buf*32768 + 16384 + qn*8192 + wave*1024;
    const u16* s = gB + (size_t)qn*K32 + k0;
    async16(d, s); async16(d + 512, s + K8);
  };
  auto loadAq = [&](int buf, int qm, bf16x8 (&af)[4][2]) {
    const u16* base = lds + buf*32768 + qm*8192 + wm*4096 + rA*64;
    #pragma unroll
    for (int mf = 0; mf < 4; mf++) {
      af[mf][0] = *(const bf16x8*)(base + mf*1024 + acol0);
      af[mf][1] = *(const bf16x8*)(base + mf*1024 + acol1);
    }
  };
  auto loadBq = [&](int buf, int qn, bf16x8 (&bq)[2][2]) {
    const u16* base = lds + buf*32768 + 16384 + qn*8192 + wn*2048 + rA*64;
    #pragma unroll
    for (int nf = 0; nf < 2; nf++) {
      bq[nf][0] = *(const bf16x8*)(base + nf*1024 + acol0);
      bq[nf][1] = *(const bf16x8*)(base + nf*1024 + acol1);
    }
  };

  constexpr int nt = KC >> 6;
  constexpr int IT = nt/2 - 1;

  stageAq(0, 0, 0); stageBq(0, 0, 0); stageBq(0, 1, 0); stageAq(0, 1, 0);
  VMC(4);
  stageAq(1, 0, 64); stageBq(1, 0, 64); stageBq(1, 1, 64);
  VMC(6);
  BAR();

  #pragma unroll 1
  for (int it = 0; it < IT; it++) {
    int kc = it*128;
    loadAq(0, 0, afA); loadBq(0, 0, b0); stageAq(1, 1, kc + 64);
    LGKM(8); BAR(); LGKM(0);
    MFMAQ(0, 0, afA, b0);
    SB0(); BAR();
    loadBq(0, 1, b1); stageAq(0, 0, kc + 128);
    BAR(); LGKM(0);
    MFMAQ(0, 1, afA, b1);
    SB0(); BAR();
    loadAq(0, 1, afB); stageBq(0, 0, kc + 128);
    BAR(); LGKM(0);
    MFMAQ(1, 0, afB, b0);
    SB0(); BAR();
    stageBq(0, 1, kc + 128);
    BAR();
    MFMAQ(1, 1, afB, b1);
    VMC(6); BAR();
    loadAq(1, 0, afA); loadBq(1, 0, b0); stageAq(0, 1, kc + 128);
    LGKM(8); BAR(); LGKM(0);
    MFMAQ(0, 0, afA, b0);
    SB0(); BAR();
    loadBq(1, 1, b1); stageAq(1, 0, kc + 192);
    BAR(); LGKM(0);
    MFMAQ(0, 1, afA, b1);
    SB0(); BAR();
    loadAq(1, 1, afB); stageBq(1, 0, kc + 192);
    BAR(); LGKM(0);
    MFMAQ(1, 0, afB, b0);
    SB0(); BAR();
    stageBq(1, 1, kc + 192);
    BAR();
    MFMAQ(1, 1, afB, b1);
    VMC(6); BAR();
  }

  {
    int kc = IT*128;
    loadAq(0, 0, afA); loadBq(0, 0, b0); stageAq(1, 1, kc + 64);
    LGKM(8); BAR(); LGKM(0);
    MFMAQ(0, 0, afA, b0);
    SB0(); BAR();
    loadBq(0, 1, b1);
    BAR(); LGKM(0);
    MFMAQ(0, 1, afA, b1);
    SB0(); BAR();
    loadAq(0, 1, afB);
    BAR(); LGKM(0);
    MFMAQ(1, 0, afB, b0);
    SB0(); BAR();
    MFMAQ(1, 1, afB, b1);
    VMC(0); BAR();
    loadAq(1, 0, afA); loadBq(1, 0, b0); SB0();
    loadBq(1, 1, b1); SB0();
    loadAq(1, 1, afB); SB0();
    LGKM(12); MFMAQ(0, 0, afA, b0);
    LGKM(8);  MFMAQ(0, 1, afA, b1);
    LGKM(0);  MFMAQ(1, 0, afB, b0);
    MFMAQ(1, 1, afB, b1);
  }

  #pragma unroll
  for (int mf = 0; mf < 8; mf++)
    #pragma unroll
    for (int nf = 0; nf < 4; nf++)
      #pragma unroll
      for (int j = 0; j < 4; j++) {
        int rr = m0 + wm*128 + mf*16 + (lane >> 4)*4 + j;
        int cc = n0 + wn*64 + nf*16 + (lane & 15);
        size_t idx = (size_t)rr * N + cc;
        float v = acc[mf][nf][j];
        if constexpr (EPI == 0) {
          ((u16*)Cv)[idx] = f2bf(v);
        } else if constexpr (EPI == 1) {
          ((float*)Cv)[idx] = v + resid[idx];
        } else {
          float g = bf2f(gate[idx]);
          float sg = g / (1.f + __expf(-g));
          ((u16*)Cv)[idx] = f2bf(sg * v);
        }
      }
}

// ---------------- Flash attention, causal, GQA 4:1 (+ hosted weight-conversion blocks) ----------------
// 4 blocks/CU: 4 x 40 KB LDS = 160 KB exactly; launch_bounds(256,4) caps VGPR at 128.
__global__ __launch_bounds__(256, 4) void attn_kernel(
    const u16* __restrict__ q, const u16* __restrict__ k,
    const u16* __restrict__ vt, u16* __restrict__ out,
    CJob j0, CJob j1, CJob j2, int kstr) {
  __shared__ __align__(16) u16 shm[20480];      // 40 KB: Ks 16K | Vs 16K | Ps 8K
  u16* Ks = shm;
  u16* Vs = shm + 8192;
  u16* Ps = shm + 16384;
  int bid = blockIdx.x;

  if (bid >= 2048) {                            // hosted conv blocks
    int cb = bid - 2048, CB = (int)gridDim.x - 2048;
    float (*tl)[65] = (float(*)[65])shm;
    int ntot = j0.ntiles + j1.ntiles + j2.ntiles;
    for (int g = cb; g < ntot; g += CB) {
      const float* in; u16* outp; int K, N, tile;
      if (g < j0.ntiles)                  { in = j0.in; outp = j0.out; K = j0.K; N = j0.N; tile = g; }
      else if (g < j0.ntiles + j1.ntiles) { in = j1.in; outp = j1.out; K = j1.K; N = j1.N; tile = g - j0.ntiles; }
      else                                { in = j2.in; outp = j2.out; K = j2.K; N = j2.N; tile = g - j0.ntiles - j1.ntiles; }
      conv_one(in, outp, K, N, tile, threadIdx.x, tl);
    }
    return;
  }

  int qt = bid & 15;
  int h  = (bid >> 4) & 31;
  int b  = bid >> 9;
  int kvh = h >> 2;
  int tid = threadIdx.x, lane = tid & 63, wave = tid >> 6;
  int q0 = qt << 6;

  bf16x8 qf[4];
  {
    const u16* qb_ = q + (size_t)(b*1024 + q0 + wave*16 + (lane & 15))*4096 + h*128 + (lane >> 4)*8;
    #pragma unroll
    for (int ks = 0; ks < 4; ks++) qf[ks] = *(const bf16x8*)(qb_ + ks*32);
  }
  f32x4 o[8];
  f32x4 zero = {0.f,0.f,0.f,0.f};
  #pragma unroll
  for (int i = 0; i < 8; i++) o[i] = zero;
  float m[4] = {-1e30f,-1e30f,-1e30f,-1e30f};
  float l[4] = {0.f,0.f,0.f,0.f};

  int kr[4], kc[4], vr[4], vc[4];
  #pragma unroll
  for (int i = 0; i < 4; i++) {
    int c = i*256 + tid;
    kr[i] = c >> 4; kc[i] = ((c & 15)*16) ^ ((kr[i] & 7) << 4);
    vr[i] = c >> 3; vc[i] = ((c & 7)*16)  ^ ((vr[i] & 7) << 4);
  }

  for (int t = 0; t <= qt; t++) {
    int kv0 = t << 6;
    #pragma unroll
    for (int i = 0; i < 4; i++) {
      async16(Ks + i*2048 + wave*512, k  + (size_t)(b*1024 + kv0 + kr[i])*kstr + kvh*128 + (kc[i] >> 1));
      async16(Vs + i*2048 + wave*512, vt + (size_t)((b*8 + kvh)*128 + vr[i])*1024 + kv0 + (vc[i] >> 1));
    }
    __syncthreads();

    f32x4 s[4];
    #pragma unroll
    for (int nf = 0; nf < 4; nf++) {
      s[nf] = zero;
      #pragma unroll
      for (int ks = 0; ks < 4; ks++) {
        int r = nf*16 + (lane & 15);
        int c2 = (ks*32 + (lane >> 4)*8)*2;
        bf16x8 kf = *(const bf16x8*)(Ks + r*128 + ((c2 ^ ((r & 7) << 4)) >> 1));
        s[nf] = __builtin_amdgcn_mfma_f32_16x16x32_bf16(qf[ks], kf, s[nf], 0, 0, 0);
      }
    }
    if (t == qt) {
      #pragma unroll
      for (int nf = 0; nf < 4; nf++)
        #pragma unroll
        for (int j = 0; j < 4; j++) {
          int cc = nf*16 + (lane & 15);
          int rr = wave*16 + (lane >> 4)*4 + j;
          if (cc > rr) s[nf][j] = -1e30f;
        }
    }
    #pragma unroll
    for (int j = 0; j < 4; j++) {
      float mx = fmaxf(fmaxf(s[0][j], s[1][j]), fmaxf(s[2][j], s[3][j]));
      #pragma unroll
      for (int d = 1; d < 16; d <<= 1) mx = fmaxf(mx, __shfl_xor(mx, d, 64));
      float mn = fmaxf(m[j], mx);
      float f = __expf(m[j] - mn);
      m[j] = mn;
      float ssum = 0.f;
      #pragma unroll
      for (int nf = 0; nf < 4; nf++) {
        float p = __expf(s[nf][j] - mn);
        s[nf][j] = p; ssum += p;
      }
      #pragma unroll
      for (int d = 1; d < 16; d <<= 1) ssum += __shfl_xor(ssum, d, 64);
      l[j] = l[j]*f + ssum;
      #pragma unroll
      for (int nf = 0; nf < 8; nf++) o[nf][j] *= f;
    }
    #pragma unroll
    for (int nf = 0; nf < 4; nf++)
      #pragma unroll
      for (int j = 0; j < 4; j++) {
        int rr = (lane >> 4)*4 + j;
        int cb2 = ((nf*16 + (lane & 15))*2) ^ ((rr & 7) << 4);
        Ps[wave*1024 + rr*64 + (cb2 >> 1)] = f2bf(s[nf][j]);
      }
    #pragma unroll
    for (int ks2 = 0; ks2 < 2; ks2++) {
      int mr = lane & 15;
      int c2 = (ks2*32 + (lane >> 4)*8)*2;
      bf16x8 pa = *(const bf16x8*)(Ps + wave*1024 + mr*64 + ((c2 ^ ((mr & 7) << 4)) >> 1));
      #pragma unroll
      for (int nf = 0; nf < 8; nf++) {
        int d = nf*16 + (lane & 15);
        bf16x8 vf = *(const bf16x8*)(Vs + d*64 + ((c2 ^ ((d & 7) << 4)) >> 1));
        o[nf] = __builtin_amdgcn_mfma_f32_16x16x32_bf16(pa, vf, o[nf], 0, 0, 0);
      }
    }
    __syncthreads();
  }

  float inv[4];
  #pragma unroll
  for (int j = 0; j < 4; j++) inv[j] = 1.f / l[j];
  u16* ob = out + (size_t)(b*1024 + q0 + wave*16)*4096 + h*128;
  #pragma unroll
  for (int nf = 0; nf < 8; nf++)
    #pragma unroll
    for (int j = 0; j < 4; j++) {
      int rr = (lane >> 4)*4 + j;
      int cc = nf*16 + (lane & 15);
      ob[(size_t)rr*4096 + cc] = f2bf(o[nf][j] * inv[j]);
    }
}

// ---------------- driver ----------------
extern "C" void kernel_launch(void* const* d_in, const int* in_sizes, int n_in,
                              void* d_out, int out_size, void* d_ws, size_t ws_size,
                              hipStream_t stream) {
  (void)in_sizes; (void)n_in; (void)out_size;
  const float* hidden = (const float*)d_in[0];
  const float* Wq  = (const float*)d_in[3];
  const float* Wk  = (const float*)d_in[4];
  const float* Wv  = (const float*)d_in[5];
  const float* Wo  = (const float*)d_in[6];
  const float* ln1 = (const float*)d_in[7];
  const float* ln2 = (const float*)d_in[8];
  const float* Wg  = (const float*)d_in[9];
  const float* Wu  = (const float*)d_in[10];
  const float* Wd  = (const float*)d_in[11];
  float* out = (float*)d_out;

  hipFuncSetAttribute((const void*)gemm256<4096,0>,  hipFuncAttributeMaxDynamicSharedMemorySize, 131072);
  hipFuncSetAttribute((const void*)gemm256<4096,1>,  hipFuncAttributeMaxDynamicSharedMemorySize, 131072);
  hipFuncSetAttribute((const void*)gemm256<4096,2>,  hipFuncAttributeMaxDynamicSharedMemorySize, 131072);
  hipFuncSetAttribute((const void*)gemm256<11008,1>, hipFuncAttributeMaxDynamicSharedMemorySize, 131072);

  char* ws = (char*)d_ws;
  size_t off = 0;
  auto alloc = [&](size_t b) { char* p = ws + off; off += (b + 4095) & ~(size_t)4095; return p; };

  u16*  wqkvT = (u16*)alloc(50331648);   // [6144][4096] bf16: wq | wk | wv (wk,wv adjacent -> merged KV GEMM)
  u16*  woT   = (u16*)alloc(33554432);
  u16*  wgT   = (u16*)alloc(90177536);   // reused for Wd after gate-GEMM
  u16*  wuT   = (u16*)alloc(90177536);
  u16*  h1    = (u16*)alloc(33554432);
  u16*  qb    = (u16*)alloc(33554432);
  u16*  kvb   = (u16*)alloc(16777216);   // [4096 tok][2048]: k = cols 0-1023, v = 1024-2047
  u16*  vtb   = (u16*)alloc(8388608);
  float* hmid = (float*)alloc(67108864);
  u16*  gb    = (u16*)alloc(90177536);
  bool fused = off <= ws_size;

  dim3 blk(256);
  if (fused) {
    u16* wqT  = wqkvT;
    u16* wkvT = wqkvT + 16777216;        // [2048][4096]
    u16* wkT  = wkvT;
    u16* wvT  = wkvT + 4194304;
    u16* wdT  = wgT;
    CJob Jq{Wq, wqT, 4096, 4096, 4096}, Jk{Wk, wkT, 4096, 1024, 1024}, Jv{Wv, wvT, 4096, 1024, 1024};
    CJob Jo{Wo, woT, 4096, 4096, 4096}, Jg{Wg, wgT, 4096, 11008, 11008}, Ju{Wu, wuT, 4096, 11008, 11008};

    conv3<<<2048, blk, 0, stream>>>(Jq, Jk, Jv);
    rmsnorm_kernel<<<4096, blk, 0, stream>>>(hidden, ln1, h1);
    gemm256<4096,0><<<256, 512, 131072, stream>>>(h1, wqT, qb, nullptr, nullptr, 4096, 4096, 256,
                                                  nullptr, nullptr, 0, 0, 0);
    // merged K+V projection: one 512-block dispatch (exactly 2/CU x 1 round)
    gemm_bt<0><<<512, blk, 0, stream>>>(h1, wkvT, kvb, nullptr, nullptr, 4096, 2048, 4096);
    rope_kernel<<<4096, blk, 0, stream>>>(qb, kvb, 2048);
    vtrans<<<dim3(4, 32, 32), dim3(32, 8), 0, stream>>>(kvb + 1024, vtb, 2048);
    attn_kernel<<<2048 + 1024, blk, 0, stream>>>(qb, kvb, vtb, h1, Jo, Jg, Ju, 2048);
    gemm256<4096,1><<<256, 512, 131072, stream>>>(h1, woT, hmid, hidden, nullptr, 4096, 4096, 256,
                                                  nullptr, nullptr, 0, 0, 0);
    rmsnorm_kernel<<<4096, blk, 0, stream>>>(hmid, ln2, qb);
    gemm256<4096,0><<<688, 512, 131072, stream>>>(qb, wgT, gb, nullptr, nullptr, 4096, 11008, 688,
                                                  nullptr, nullptr, 0, 0, 0);
    gemm256<4096,2><<<688 + 344, 512, 131072, stream>>>(qb, wuT, gb, nullptr, gb, 4096, 11008, 688,
                                                        Wd, wdT, 11008, 4096, 11008);
    gemm256<11008,1><<<256, 512, 131072, stream>>>(gb, wdT, out, hmid, nullptr, 4096, 4096, 256,
                                                   nullptr, nullptr, 0, 0, 0);
  } else {
    // serial fallback
    off = 0;
    u16*  W1   = (u16*)alloc(90177536);
    u16*  h1s  = (u16*)alloc(33554432);
    u16*  qbs  = (u16*)alloc(33554432);
    u16*  kvbs = (u16*)alloc(16777216);
    u16*  vtbs = (u16*)alloc(8388608);
    float* hmids = (float*)alloc(67108864);
    u16*  gbs  = (u16*)alloc(90177536);
    if (off > ws_size) return;
    u16* wqT  = W1;
    u16* wkvT = W1 + 16777216;
    conv_t<<<dim3(64, 64),  blk, 0, stream>>>(Wq, wqT, 4096, 4096);
    conv_t<<<dim3(16, 64),  blk, 0, stream>>>(Wk, wkvT, 4096, 1024);
    conv_t<<<dim3(16, 64),  blk, 0, stream>>>(Wv, wkvT + 4194304, 4096, 1024);
    rmsnorm_kernel<<<4096, blk, 0, stream>>>(hidden, ln1, h1s);
    gemm256<4096,0><<<256, 512, 131072, stream>>>(h1s, wqT, qbs, nullptr, nullptr, 4096, 4096, 256,
                                                  nullptr, nullptr, 0, 0, 0);
    gemm_bt<0><<<512, blk, 0, stream>>>(h1s, wkvT, kvbs, nullptr, nullptr, 4096, 2048, 4096);
    rope_kernel<<<4096, blk, 0, stream>>>(qbs, kvbs, 2048);
    vtrans<<<dim3(4, 32, 32), dim3(32, 8), 0, stream>>>(kvbs + 1024, vtbs, 2048);
    CJob J0{nullptr, nullptr, 0, 64, 0};
    attn_kernel<<<2048, blk, 0, stream>>>(qbs, kvbs, vtbs, h1s, J0, J0, J0, 2048);
    conv_t<<<dim3(64, 64), blk, 0, stream>>>(Wo, W1, 4096, 4096);
    gemm256<4096,1><<<256, 512, 131072, stream>>>(h1s, W1, hmids, hidden, nullptr, 4096, 4096, 256,
                                                  nullptr, nullptr, 0, 0, 0);
    rmsnorm_kernel<<<4096, blk, 0, stream>>>(hmids, ln2, qbs);
    conv_t<<<dim3(172, 64), blk, 0, stream>>>(Wg, W1, 4096, 11008);
    gemm256<4096,0><<<688, 512, 131072, stream>>>(qbs, W1, gbs, nullptr, nullptr, 4096, 11008, 688,
                                                  nullptr, nullptr, 0, 0, 0);
    conv_t<<<dim3(172, 64), blk, 0, stream>>>(Wu, W1, 4096, 11008);
    gemm256<4096,2><<<688, 512, 131072, stream>>>(qbs, W1, gbs, nullptr, gbs, 4096, 11008, 688,
                                                  nullptr, nullptr, 0, 0, 0);
    conv_t<<<dim3(64, 172), blk, 0, stream>>>(Wd, W1, 11008, 4096);
    gemm256<11008,1><<<256, 512, 131072, stream>>>(gbs, W1, out, hmids, nullptr, 4096, 4096, 256,
                                                   nullptr, nullptr, 0, 0, 0);
  }
}

// Round 8
// 1625.230 us; speedup vs baseline: 1.1297x; 1.0246x over previous
//
#include <hip/hip_runtime.h>

#define DEVINL __device__ __forceinline__

typedef unsigned short u16;
typedef __attribute__((ext_vector_type(8))) short bf16x8;   // 8 bf16 = 4 VGPRs (MFMA A/B frag)
typedef __attribute__((ext_vector_type(4))) float f32x4;     // MFMA C/D frag
typedef __attribute__((ext_vector_type(4))) unsigned short u16x4;

// B=4, S=1024, HID=4096, NH=32, NKV=8, HD=128, FF=11008

DEVINL float bf2f(u16 u) { union { unsigned i; float f; } x; x.i = ((unsigned)u) << 16; return x.f; }
DEVINL u16 f2bf(float f) {                       // round-to-nearest-even
  union { float f; unsigned i; } x; x.f = f;
  unsigned r = x.i + 0x7fffu + ((x.i >> 16) & 1u);
  return (u16)(r >> 16);
}

DEVINL void async16(u16* lds, const u16* g) {
  __builtin_amdgcn_global_load_lds((const __attribute__((address_space(1))) unsigned*)g,
                                   (__attribute__((address_space(3))) unsigned*)lds, 16, 0, 0);
}

struct CJob { const float* in; u16* out; int K, N, ntiles; int mode; };
// mode 0: out row = col index n (plain transpose)
// mode 1: gate-interleave: row = (n>>5)*64 + (n&31)
// mode 2: up-interleave:   row = (n>>5)*64 + 32 + (n&31)

// one 64x64 convert+transpose tile; 256 participating threads; 2 block-wide syncs
DEVINL void conv_one(const float* __restrict__ in, u16* __restrict__ out,
                     int K, int N, int tile, int t, float (*tl)[65], int mode) {
  int tn = N >> 6;
  int kt = tile / tn;
  int k0 = kt << 6, n0 = (tile - kt*tn) << 6;
  int r = t >> 4, c4 = (t & 15) << 2;
  #pragma unroll
  for (int it = 0; it < 4; it++) {
    int row = r + it*16;
    f32x4 v = *(const f32x4*)(in + (size_t)(k0 + row)*N + n0 + c4);
    tl[row][c4+0] = v[0]; tl[row][c4+1] = v[1];
    tl[row][c4+2] = v[2]; tl[row][c4+3] = v[3];
  }
  __syncthreads();
  #pragma unroll
  for (int it = 0; it < 4; it++) {
    int nrow = r + it*16;
    u16x4 ov;
    #pragma unroll
    for (int e = 0; e < 4; e++) ov[e] = f2bf(tl[c4+e][nrow]);
    int orow = n0 + nrow;
    if (mode == 1)      orow = ((orow >> 5) << 6) + (orow & 31);
    else if (mode == 2) orow = ((orow >> 5) << 6) + 32 + (orow & 31);
    *(u16x4*)(out + (size_t)orow*K + k0 + c4) = ov;
  }
  __syncthreads();
}

// ---------------- standalone conv (QKV), grid-stride over 3 jobs ----------------
__global__ __launch_bounds__(256) void conv3(CJob j0, CJob j1, CJob j2) {
  __shared__ float tl[64][65];
  int ntot = j0.ntiles + j1.ntiles + j2.ntiles;
  for (int g = blockIdx.x; g < ntot; g += gridDim.x) {
    CJob* jp;
    int tile;
    if (g < j0.ntiles)                 { jp = &j0; tile = g; }
    else if (g < j0.ntiles + j1.ntiles){ jp = &j1; tile = g - j0.ntiles; }
    else                               { jp = &j2; tile = g - j0.ntiles - j1.ntiles; }
    conv_one(jp->in, jp->out, jp->K, jp->N, tile, threadIdx.x, tl, jp->mode);
  }
}

// ---------------- legacy conv (serial fallback path) ----------------
__global__ __launch_bounds__(256) void conv_t(const float* __restrict__ in,
                                              u16* __restrict__ out, int K, int N) {
  __shared__ float tl[64][65];
  int tile = blockIdx.y * gridDim.x + blockIdx.x;
  conv_one(in, out, K, N, tile, threadIdx.x, tl, 0);
}

// ---------------- RMSNorm: fp32 in [4096 rows x 4096] -> bf16 out ----------------
__global__ __launch_bounds__(256) void rmsnorm_kernel(const float* __restrict__ x,
                                                      const float* __restrict__ w,
                                                      u16* __restrict__ out) {
  int row = blockIdx.x, t = threadIdx.x;
  const float* xr = x + (size_t)row * 4096;
  f32x4 v[4];
  float ss = 0.f;
  #pragma unroll
  for (int i = 0; i < 4; i++) {
    v[i] = *(const f32x4*)(xr + (t + 256*i)*4);
    ss += v[i][0]*v[i][0] + v[i][1]*v[i][1] + v[i][2]*v[i][2] + v[i][3]*v[i][3];
  }
  #pragma unroll
  for (int d = 1; d < 64; d <<= 1) ss += __shfl_xor(ss, d, 64);
  __shared__ float ps[4];
  if ((t & 63) == 0) ps[t >> 6] = ss;
  __syncthreads();
  float scale = rsqrtf((ps[0]+ps[1]+ps[2]+ps[3]) * (1.f/4096.f) + 1e-6f);
  #pragma unroll
  for (int i = 0; i < 4; i++) {
    f32x4 wv = *(const f32x4*)(w + (t + 256*i)*4);
    u16x4 o;
    #pragma unroll
    for (int e = 0; e < 4; e++) o[e] = f2bf(v[i][e] * scale * wv[e]);
    *(u16x4*)(out + (size_t)row*4096 + (t + 256*i)*4) = o;
  }
}

// ---------------- RoPE in-place on q [tok,4096] & k [tok, kstr]; q gets 1/sqrt(HD) ----------------
__global__ __launch_bounds__(256) void rope_kernel(u16* __restrict__ q, u16* __restrict__ k, int kstr) {
  int tok = blockIdx.x;
  int s = tok & 1023;
  __shared__ float cs[64], sn[64];
  int t = threadIdx.x;
  if (t < 64) {
    float inv = __expf(-(float)t * 0.14391156934f);
    float ang = (float)s * inv;
    cs[t] = cosf(ang); sn[t] = sinf(ang);
  }
  __syncthreads();
  const float qscale = 0.08838834764831845f;
  size_t qbase = (size_t)tok * 4096;
  #pragma unroll
  for (int it = 0; it < 8; it++) {
    int item = t + it*256; int h = item >> 6, j = item & 63;
    size_t i0 = qbase + h*128 + j;
    float x1 = bf2f(q[i0]), x2 = bf2f(q[i0+64]);
    float c = cs[j], si = sn[j];
    q[i0]    = f2bf((x1*c - x2*si) * qscale);
    q[i0+64] = f2bf((x2*c + x1*si) * qscale);
  }
  size_t kbase = (size_t)tok * kstr;
  #pragma unroll
  for (int it = 0; it < 2; it++) {
    int item = t + it*256; int h = item >> 6, j = item & 63;
    size_t i0 = kbase + h*128 + j;
    float x1 = bf2f(k[i0]), x2 = bf2f(k[i0+64]);
    float c = cs[j], si = sn[j];
    k[i0]    = f2bf(x1*c - x2*si);
    k[i0+64] = f2bf(x2*c + x1*si);
  }
}

// ---------------- V transpose per (b,kvh): [1024 x 128] (stride vstr) -> vt [128 x 1024] ----------------
__global__ __launch_bounds__(256) void vtrans(const u16* __restrict__ v, u16* __restrict__ vt, int vstr) {
  __shared__ u16 tile[32][33];
  int bh = blockIdx.z; int b = bh >> 3, kvh = bh & 7;
  int d0 = blockIdx.x << 5, s0 = blockIdx.y << 5;
  int tx = threadIdx.x, ty = threadIdx.y;
  for (int r = ty; r < 32; r += 8)
    tile[r][tx] = v[(size_t)(b*1024 + s0 + r)*vstr + kvh*128 + d0 + tx];
  __syncthreads();
  for (int r = ty; r < 32; r += 8)
    vt[(size_t)((b*8 + kvh)*128 + d0 + r)*1024 + s0 + tx] = tile[tx][r];
}

// ---------------- 128-tile GEMM (merged K+V projection) ----------------
template<int EPI>
__global__ __launch_bounds__(256, 2) void gemm_bt(
    const u16* __restrict__ A, const u16* __restrict__ Bt,
    void* __restrict__ Cv, const float* __restrict__ resid,
    const u16* __restrict__ gate, int M, int N, int K) {
  __shared__ u16 As[128*64];
  __shared__ u16 Bs[128*64];
  int nwg = gridDim.x;
  int bid = (int)blockIdx.x;
  int cpx = nwg >> 3;
  int swz = (bid & 7) * cpx + (bid >> 3);
  int mt = M >> 7;
  int m0 = (swz % mt) << 7;
  int n0 = (swz / mt) << 7;
  int tid = threadIdx.x;
  int lane = tid & 63, wave = tid >> 6;
  int wm = wave >> 1, wn = wave & 1;

  f32x4 acc[4][4];
  f32x4 zero = {0.f, 0.f, 0.f, 0.f};
  #pragma unroll
  for (int i = 0; i < 4; i++)
    #pragma unroll
    for (int j = 0; j < 4; j++) acc[i][j] = zero;

  int arow[4], acolb[4];
  #pragma unroll
  for (int i = 0; i < 4; i++) {
    int c = i*256 + tid;
    arow[i]  = c >> 3;
    acolb[i] = ((c & 7) * 16) ^ ((arow[i] & 7) << 4);
  }

  int nsteps = K >> 6;
  for (int t = 0; t < nsteps; t++) {
    int k0 = t << 6;
    #pragma unroll
    for (int i = 0; i < 4; i++) {
      async16(As + i*2048 + wave*512, A  + (size_t)(m0 + arow[i])*K + k0 + (acolb[i] >> 1));
      async16(Bs + i*2048 + wave*512, Bt + (size_t)(n0 + arow[i])*K + k0 + (acolb[i] >> 1));
    }
    __syncthreads();
    #pragma unroll
    for (int ks = 0; ks < 2; ks++) {
      bf16x8 af[4], bfr[4];
      int c2 = (ks*32 + (lane >> 4)*8) * 2;
      #pragma unroll
      for (int mf = 0; mf < 4; mf++) {
        int r = wm*64 + mf*16 + (lane & 15);
        af[mf] = *(const bf16x8*)(As + r*64 + ((c2 ^ ((r & 7) << 4)) >> 1));
      }
      #pragma unroll
      for (int nf = 0; nf < 4; nf++) {
        int r = wn*64 + nf*16 + (lane & 15);
        bfr[nf] = *(const bf16x8*)(Bs + r*64 + ((c2 ^ ((r & 7) << 4)) >> 1));
      }
      #pragma unroll
      for (int mf = 0; mf < 4; mf++)
        #pragma unroll
        for (int nf = 0; nf < 4; nf++)
          acc[mf][nf] = __builtin_amdgcn_mfma_f32_16x16x32_bf16(af[mf], bfr[nf], acc[mf][nf], 0, 0, 0);
    }
    __syncthreads();
  }

  #pragma unroll
  for (int mf = 0; mf < 4; mf++)
    #pragma unroll
    for (int nf = 0; nf < 4; nf++)
      #pragma unroll
      for (int j = 0; j < 4; j++) {
        int rr = m0 + wm*64 + mf*16 + (lane >> 4)*4 + j;
        int cc = n0 + wn*64 + nf*16 + (lane & 15);
        size_t idx = (size_t)rr * N + cc;
        float v = acc[mf][nf][j];
        if constexpr (EPI == 0) {
          ((u16*)Cv)[idx] = f2bf(v);
        } else if constexpr (EPI == 1) {
          ((float*)Cv)[idx] = v + resid[idx];
        } else {
          float g = bf2f(gate[idx]);
          float sg = g / (1.f + __expf(-g));
          ((u16*)Cv)[idx] = f2bf(sg * v);
        }
      }
}

// ---------------- 256x256 GEMM: 8-phase / 2-K-tile unrolled, STATIC buffers ----------
// EPI: 0 = bf16 C; 1 = fp32 C + resid; 2 = bf16 C = silu(gate)*acc;
//      3 = interleaved gate/up (B rows: 64-row groups = 32 gate cols + 32 up cols);
//          epilogue computes act = silu(g)*u in-register, writes [M][11008] bf16.
#define SB0() __builtin_amdgcn_sched_barrier(0)
#define BAR() __builtin_amdgcn_s_barrier()
#define LGKM(n) do { SB0(); asm volatile("s_waitcnt lgkmcnt(" #n ")" ::: "memory"); SB0(); } while (0)
#define VMC(n)  do { SB0(); asm volatile("s_waitcnt vmcnt(" #n ")"  ::: "memory"); SB0(); } while (0)
#define MFMAQ(qm, qn, AF, BQ) do { \
  __builtin_amdgcn_s_setprio(1); \
  _Pragma("unroll") for (int mf_ = 0; mf_ < 4; mf_++) \
  _Pragma("unroll") for (int nf_ = 0; nf_ < 2; nf_++) \
  _Pragma("unroll") for (int ks_ = 0; ks_ < 2; ks_++) \
    acc[(qm)*4+mf_][(qn)*2+nf_] = __builtin_amdgcn_mfma_f32_16x16x32_bf16( \
        AF[mf_][ks_], BQ[nf_][ks_], acc[(qm)*4+mf_][(qn)*2+nf_], 0, 0, 0); \
  __builtin_amdgcn_s_setprio(0); } while (0)

template<int KC, int EPI>
__global__ __launch_bounds__(512, 2) void gemm256(
    const u16* __restrict__ A, const u16* __restrict__ Bt,
    void* __restrict__ Cv, const float* __restrict__ resid,
    const u16* __restrict__ gate, int M, int N, int G,
    const float* __restrict__ cvin, u16* __restrict__ cvout, int cvK, int cvN, int cvTiles, int cvMode) {
  extern __shared__ u16 lds[];
  int bid = (int)blockIdx.x;
  int tid = threadIdx.x;

  if (bid >= G) {                               // hosted conv blocks
    int cb = bid - G, CB = (int)gridDim.x - G;
    int h = tid >> 8, t = tid & 255;
    float (*tl)[65] = (float(*)[65])((char*)lds + h*16896);
    int pairs = cvTiles >> 1;
    for (int p = cb; p < pairs; p += CB)
      conv_one(cvin, cvout, cvK, cvN, 2*p + h, t, tl, cvMode);
    return;
  }

  int cpx = G >> 3;
  int swz = (bid & 7) * cpx + (bid >> 3);       // XCD swizzle (T1); G % 8 == 0
  int mt = M >> 8;
  int m0 = (swz % mt) << 8;
  int n0 = (swz / mt) << 8;
  int lane = tid & 63, wave = tid >> 6;
  int wm = wave >> 2, wn = wave & 3;

  f32x4 acc[8][4];
  f32x4 zero = {0.f, 0.f, 0.f, 0.f};
  #pragma unroll
  for (int i = 0; i < 8; i++)
    #pragma unroll
    for (int j = 0; j < 4; j++) acc[i][j] = zero;

  int sCol = ((lane & 7) ^ (lane >> 3)) << 3;
  int aRow = (wave >> 2)*128 + (wave & 3)*16 + (lane >> 3);
  int bRow = (wave >> 1)*64  + (wave & 1)*16 + (lane >> 3);
  const u16* gA = A  + (size_t)(m0 + aRow) * KC + sCol;
  const u16* gB = Bt + (size_t)(n0 + bRow) * KC + sCol;
  constexpr size_t K8 = (size_t)8 * KC, K32 = (size_t)32 * KC, K64 = (size_t)64 * KC;

  int rA = lane & 15;
  int acol0 = (((lane >> 4)    ) ^ (rA & 7)) << 3;
  int acol1 = (((lane >> 4) + 4) ^ (rA & 7)) << 3;

  bf16x8 afA[4][2], afB[4][2], b0[2][2], b1[2][2];

  auto stageAq = [&](int buf, int qm, int k0) {
    u16* d = lds + buf*32768 + qm*8192 + wave*1024;
    const u16* s = gA + (size_t)qm*K64 + k0;
    async16(d, s); async16(d + 512, s + K8);
  };
  auto stageBq = [&](int buf, int qn, int k0) {
    u16* d = lds + buf*32768 + 16384 + qn*8192 + wave*1024;
    const u16* s = gB + (size_t)qn*K32 + k0;
    async16(d, s); async16(d + 512, s + K8);
  };
  auto loadAq = [&](int buf, int qm, bf16x8 (&af)[4][2]) {
    const u16* base = lds + buf*32768 + qm*8192 + wm*4096 + rA*64;
    #pragma unroll
    for (int mf = 0; mf < 4; mf++) {
      af[mf][0] = *(const bf16x8*)(base + mf*1024 + acol0);
      af[mf][1] = *(const bf16x8*)(base + mf*1024 + acol1);
    }
  };
  auto loadBq = [&](int buf, int qn, bf16x8 (&bq)[2][2]) {
    const u16* base = lds + buf*32768 + 16384 + qn*8192 + wn*2048 + rA*64;
    #pragma unroll
    for (int nf = 0; nf < 2; nf++) {
      bq[nf][0] = *(const bf16x8*)(base + nf*1024 + acol0);
      bq[nf][1] = *(const bf16x8*)(base + nf*1024 + acol1);
    }
  };

  constexpr int nt = KC >> 6;
  constexpr int IT = nt/2 - 1;

  stageAq(0, 0, 0); stageBq(0, 0, 0); stageBq(0, 1, 0); stageAq(0, 1, 0);
  VMC(4);
  stageAq(1, 0, 64); stageBq(1, 0, 64); stageBq(1, 1, 64);
  VMC(6);
  BAR();

  #pragma unroll 1
  for (int it = 0; it < IT; it++) {
    int kc = it*128;
    loadAq(0, 0, afA); loadBq(0, 0, b0); stageAq(1, 1, kc + 64);
    LGKM(8); BAR(); LGKM(0);
    MFMAQ(0, 0, afA, b0);
    SB0(); BAR();
    loadBq(0, 1, b1); stageAq(0, 0, kc + 128);
    BAR(); LGKM(0);
    MFMAQ(0, 1, afA, b1);
    SB0(); BAR();
    loadAq(0, 1, afB); stageBq(0, 0, kc + 128);
    BAR(); LGKM(0);
    MFMAQ(1, 0, afB, b0);
    SB0(); BAR();
    stageBq(0, 1, kc + 128);
    BAR();
    MFMAQ(1, 1, afB, b1);
    VMC(6); BAR();
    loadAq(1, 0, afA); loadBq(1, 0, b0); stageAq(0, 1, kc + 128);
    LGKM(8); BAR(); LGKM(0);
    MFMAQ(0, 0, afA, b0);
    SB0(); BAR();
    loadBq(1, 1, b1); stageAq(1, 0, kc + 192);
    BAR(); LGKM(0);
    MFMAQ(0, 1, afA, b1);
    SB0(); BAR();
    loadAq(1, 1, afB); stageBq(1, 0, kc + 192);
    BAR(); LGKM(0);
    MFMAQ(1, 0, afB, b0);
    SB0(); BAR();
    stageBq(1, 1, kc + 192);
    BAR();
    MFMAQ(1, 1, afB, b1);
    VMC(6); BAR();
  }

  {
    int kc = IT*128;
    loadAq(0, 0, afA); loadBq(0, 0, b0); stageAq(1, 1, kc + 64);
    LGKM(8); BAR(); LGKM(0);
    MFMAQ(0, 0, afA, b0);
    SB0(); BAR();
    loadBq(0, 1, b1);
    BAR(); LGKM(0);
    MFMAQ(0, 1, afA, b1);
    SB0(); BAR();
    loadAq(0, 1, afB);
    BAR(); LGKM(0);
    MFMAQ(1, 0, afB, b0);
    SB0(); BAR();
    MFMAQ(1, 1, afB, b1);
    VMC(0); BAR();
    loadAq(1, 0, afA); loadBq(1, 0, b0); SB0();
    loadBq(1, 1, b1); SB0();
    loadAq(1, 1, afB); SB0();
    LGKM(12); MFMAQ(0, 0, afA, b0);
    LGKM(8);  MFMAQ(0, 1, afA, b1);
    LGKM(0);  MFMAQ(1, 0, afB, b0);
    MFMAQ(1, 1, afB, b1);
  }

  if constexpr (EPI == 3) {
    // acc[mf][nf] (nf=0,1) = gate, acc[mf][nf+2] = up, SAME output column (in-thread pairing)
    int colb = (n0 >> 1) + wn*32 + (lane & 15);
    #pragma unroll
    for (int mf = 0; mf < 8; mf++)
      #pragma unroll
      for (int nf = 0; nf < 2; nf++)
        #pragma unroll
        for (int j = 0; j < 4; j++) {
          int rr = m0 + wm*128 + mf*16 + (lane >> 4)*4 + j;
          float g = acc[mf][nf][j];
          float u = acc[mf][nf+2][j];
          float sg = g / (1.f + __expf(-g));
          ((u16*)Cv)[(size_t)rr * 11008 + colb + nf*16] = f2bf(sg * u);
        }
  } else {
    #pragma unroll
    for (int mf = 0; mf < 8; mf++)
      #pragma unroll
      for (int nf = 0; nf < 4; nf++)
        #pragma unroll
        for (int j = 0; j < 4; j++) {
          int rr = m0 + wm*128 + mf*16 + (lane >> 4)*4 + j;
          int cc = n0 + wn*64 + nf*16 + (lane & 15);
          size_t idx = (size_t)rr * N + cc;
          float v = acc[mf][nf][j];
          if constexpr (EPI == 0) {
            ((u16*)Cv)[idx] = f2bf(v);
          } else if constexpr (EPI == 1) {
            ((float*)Cv)[idx] = v + resid[idx];
          } else if constexpr (EPI == 2) {
            float g = bf2f(gate[idx]);
            float sg = g / (1.f + __expf(-g));
            ((u16*)Cv)[idx] = f2bf(sg * v);
          }
        }
  }
}

// ---------------- Flash attention, causal, GQA 4:1 (+ hosted weight-conversion blocks) ----------------
__global__ __launch_bounds__(256, 4) void attn_kernel(
    const u16* __restrict__ q, const u16* __restrict__ k,
    const u16* __restrict__ vt, u16* __restrict__ out,
    CJob j0, CJob j1, CJob j2, int kstr) {
  __shared__ __align__(16) u16 shm[20480];      // 40 KB: Ks 16K | Vs 16K | Ps 8K
  u16* Ks = shm;
  u16* Vs = shm + 8192;
  u16* Ps = shm + 16384;
  int bid = blockIdx.x;

  if (bid >= 2048) {                            // hosted conv blocks
    int cb = bid - 2048, CB = (int)gridDim.x - 2048;
    float (*tl)[65] = (float(*)[65])shm;
    int ntot = j0.ntiles + j1.ntiles + j2.ntiles;
    for (int g = cb; g < ntot; g += CB) {
      CJob* jp; int tile;
      if (g < j0.ntiles)                  { jp = &j0; tile = g; }
      else if (g < j0.ntiles + j1.ntiles) { jp = &j1; tile = g - j0.ntiles; }
      else                                { jp = &j2; tile = g - j0.ntiles - j1.ntiles; }
      conv_one(jp->in, jp->out, jp->K, jp->N, tile, threadIdx.x, tl, jp->mode);
    }
    return;
  }

  int qt = bid & 15;
  int h  = (bid >> 4) & 31;
  int b  = bid >> 9;
  int kvh = h >> 2;
  int tid = threadIdx.x, lane = tid & 63, wave = tid >> 6;
  int q0 = qt << 6;

  bf16x8 qf[4];
  {
    const u16* qb_ = q + (size_t)(b*1024 + q0 + wave*16 + (lane & 15))*4096 + h*128 + (lane >> 4)*8;
    #pragma unroll
    for (int ks = 0; ks < 4; ks++) qf[ks] = *(const bf16x8*)(qb_ + ks*32);
  }
  f32x4 o[8];
  f32x4 zero = {0.f,0.f,0.f,0.f};
  #pragma unroll
  for (int i = 0; i < 8; i++) o[i] = zero;
  float m[4] = {-1e30f,-1e30f,-1e30f,-1e30f};
  float l[4] = {0.f,0.f,0.f,0.f};

  int kr[4], kc[4], vr[4], vc[4];
  #pragma unroll
  for (int i = 0; i < 4; i++) {
    int c = i*256 + tid;
    kr[i] = c >> 4; kc[i] = ((c & 15)*16) ^ ((kr[i] & 7) << 4);
    vr[i] = c >> 3; vc[i] = ((c & 7)*16)  ^ ((vr[i] & 7) << 4);
  }

  for (int t = 0; t <= qt; t++) {
    int kv0 = t << 6;
    #pragma unroll
    for (int i = 0; i < 4; i++) {
      async16(Ks + i*2048 + wave*512, k  + (size_t)(b*1024 + kv0 + kr[i])*kstr + kvh*128 + (kc[i] >> 1));
      async16(Vs + i*2048 + wave*512, vt + (size_t)((b*8 + kvh)*128 + vr[i])*1024 + kv0 + (vc[i] >> 1));
    }
    __syncthreads();

    f32x4 s[4];
    #pragma unroll
    for (int nf = 0; nf < 4; nf++) {
      s[nf] = zero;
      #pragma unroll
      for (int ks = 0; ks < 4; ks++) {
        int r = nf*16 + (lane & 15);
        int c2 = (ks*32 + (lane >> 4)*8)*2;
        bf16x8 kf = *(const bf16x8*)(Ks + r*128 + ((c2 ^ ((r & 7) << 4)) >> 1));
        s[nf] = __builtin_amdgcn_mfma_f32_16x16x32_bf16(qf[ks], kf, s[nf], 0, 0, 0);
      }
    }
    if (t == qt) {
      #pragma unroll
      for (int nf = 0; nf < 4; nf++)
        #pragma unroll
        for (int j = 0; j < 4; j++) {
          int cc = nf*16 + (lane & 15);
          int rr = wave*16 + (lane >> 4)*4 + j;
          if (cc > rr) s[nf][j] = -1e30f;
        }
    }
    #pragma unroll
    for (int j = 0; j < 4; j++) {
      float mx = fmaxf(fmaxf(s[0][j], s[1][j]), fmaxf(s[2][j], s[3][j]));
      #pragma unroll
      for (int d = 1; d < 16; d <<= 1) mx = fmaxf(mx, __shfl_xor(mx, d, 64));
      float mn = fmaxf(m[j], mx);
      float f = __expf(m[j] - mn);
      m[j] = mn;
      float ssum = 0.f;
      #pragma unroll
      for (int nf = 0; nf < 4; nf++) {
        float p = __expf(s[nf][j] - mn);
        s[nf][j] = p; ssum += p;
      }
      #pragma unroll
      for (int d = 1; d < 16; d <<= 1) ssum += __shfl_xor(ssum, d, 64);
      l[j] = l[j]*f + ssum;
      #pragma unroll
      for (int nf = 0; nf < 8; nf++) o[nf][j] *= f;
    }
    #pragma unroll
    for (int nf = 0; nf < 4; nf++)
      #pragma unroll
      for (int j = 0; j < 4; j++) {
        int rr = (lane >> 4)*4 + j;
        int cb2 = ((nf*16 + (lane & 15))*2) ^ ((rr & 7) << 4);
        Ps[wave*1024 + rr*64 + (cb2 >> 1)] = f2bf(s[nf][j]);
      }
    #pragma unroll
    for (int ks2 = 0; ks2 < 2; ks2++) {
      int mr = lane & 15;
      int c2 = (ks2*32 + (lane >> 4)*8)*2;
      bf16x8 pa = *(const bf16x8*)(Ps + wave*1024 + mr*64 + ((c2 ^ ((mr & 7) << 4)) >> 1));
      #pragma unroll
      for (int nf = 0; nf < 8; nf++) {
        int d = nf*16 + (lane & 15);
        bf16x8 vf = *(const bf16x8*)(Vs + d*64 + ((c2 ^ ((d & 7) << 4)) >> 1));
        o[nf] = __builtin_amdgcn_mfma_f32_16x16x32_bf16(pa, vf, o[nf], 0, 0, 0);
      }
    }
    __syncthreads();
  }

  float inv[4];
  #pragma unroll
  for (int j = 0; j < 4; j++) inv[j] = 1.f / l[j];
  u16* ob = out + (size_t)(b*1024 + q0 + wave*16)*4096 + h*128;
  #pragma unroll
  for (int nf = 0; nf < 8; nf++)
    #pragma unroll
    for (int j = 0; j < 4; j++) {
      int rr = (lane >> 4)*4 + j;
      int cc = nf*16 + (lane & 15);
      ob[(size_t)rr*4096 + cc] = f2bf(o[nf][j] * inv[j]);
    }
}

// ---------------- driver ----------------
extern "C" void kernel_launch(void* const* d_in, const int* in_sizes, int n_in,
                              void* d_out, int out_size, void* d_ws, size_t ws_size,
                              hipStream_t stream) {
  (void)in_sizes; (void)n_in; (void)out_size;
  const float* hidden = (const float*)d_in[0];
  const float* Wq  = (const float*)d_in[3];
  const float* Wk  = (const float*)d_in[4];
  const float* Wv  = (const float*)d_in[5];
  const float* Wo  = (const float*)d_in[6];
  const float* ln1 = (const float*)d_in[7];
  const float* ln2 = (const float*)d_in[8];
  const float* Wg  = (const float*)d_in[9];
  const float* Wu  = (const float*)d_in[10];
  const float* Wd  = (const float*)d_in[11];
  float* out = (float*)d_out;

  hipFuncSetAttribute((const void*)gemm256<4096,0>,  hipFuncAttributeMaxDynamicSharedMemorySize, 131072);
  hipFuncSetAttribute((const void*)gemm256<4096,1>,  hipFuncAttributeMaxDynamicSharedMemorySize, 131072);
  hipFuncSetAttribute((const void*)gemm256<4096,2>,  hipFuncAttributeMaxDynamicSharedMemorySize, 131072);
  hipFuncSetAttribute((const void*)gemm256<4096,3>,  hipFuncAttributeMaxDynamicSharedMemorySize, 131072);
  hipFuncSetAttribute((const void*)gemm256<11008,1>, hipFuncAttributeMaxDynamicSharedMemorySize, 131072);

  char* ws = (char*)d_ws;
  size_t off = 0;
  auto alloc = [&](size_t b) { char* p = ws + off; off += (b + 4095) & ~(size_t)4095; return p; };

  u16*  wqkvT = (u16*)alloc(50331648);   // [6144][4096] bf16: wq | wk | wv
  u16*  woT   = (u16*)alloc(33554432);
  (void)alloc(8388608);                  // pad: lets wdT (86 MiB) alias wqkvT+woT+pad
  u16*  wguT  = (u16*)alloc(180355072);  // [22016][4096] interleaved gate/up (64-row = 32g+32u)
  u16*  h1    = (u16*)alloc(33554432);
  u16*  qb    = (u16*)alloc(33554432);
  u16*  kvb   = (u16*)alloc(16777216);   // [4096 tok][2048]: k | v
  u16*  vtb   = (u16*)alloc(8388608);
  float* hmid = (float*)alloc(67108864);
  u16*  gb    = (u16*)alloc(90177536);   // act [4096][11008] bf16
  bool fused = off <= ws_size;

  dim3 blk(256);
  if (fused) {
    u16* wqT  = wqkvT;
    u16* wkvT = wqkvT + 16777216;
    u16* wkT  = wkvT;
    u16* wvT  = wkvT + 4194304;
    u16* wdT  = wqkvT;                   // aliases wqkvT+woT+pad, both dead by gateup time
    CJob Jq{Wq, wqT, 4096, 4096, 4096, 0}, Jk{Wk, wkT, 4096, 1024, 1024, 0}, Jv{Wv, wvT, 4096, 1024, 1024, 0};
    CJob Jo{Wo, woT, 4096, 4096, 4096, 0};
    CJob Jg{Wg, wguT, 4096, 11008, 11008, 1}, Ju{Wu, wguT, 4096, 11008, 11008, 2};

    conv3<<<2048, blk, 0, stream>>>(Jq, Jk, Jv);
    rmsnorm_kernel<<<4096, blk, 0, stream>>>(hidden, ln1, h1);
    gemm256<4096,0><<<256, 512, 131072, stream>>>(h1, wqT, qb, nullptr, nullptr, 4096, 4096, 256,
                                                  nullptr, nullptr, 0, 0, 0, 0);
    gemm_bt<0><<<512, blk, 0, stream>>>(h1, wkvT, kvb, nullptr, nullptr, 4096, 2048, 4096);
    rope_kernel<<<4096, blk, 0, stream>>>(qb, kvb, 2048);
    vtrans<<<dim3(4, 32, 32), dim3(32, 8), 0, stream>>>(kvb + 1024, vtb, 2048);
    // attention + hosted conversions of Wo (plain), Wg/Wu (interleaved into wguT)
    attn_kernel<<<2048 + 1024, blk, 0, stream>>>(qb, kvb, vtb, h1, Jo, Jg, Ju, 2048);
    gemm256<4096,1><<<256, 512, 131072, stream>>>(h1, woT, hmid, hidden, nullptr, 4096, 4096, 256,
                                                  nullptr, nullptr, 0, 0, 0, 0);
    rmsnorm_kernel<<<4096, blk, 0, stream>>>(hmid, ln2, qb);
    // merged gate+up GEMM (N=22016 B-rows -> act [4096][11008]) + hosted Wd conversion
    gemm256<4096,3><<<1376 + 344, 512, 131072, stream>>>(qb, wguT, gb, nullptr, nullptr, 4096, 11008, 1376,
                                                         Wd, wdT, 11008, 4096, 11008, 0);
    gemm256<11008,1><<<256, 512, 131072, stream>>>(gb, wdT, out, hmid, nullptr, 4096, 4096, 256,
                                                   nullptr, nullptr, 0, 0, 0, 0);
  } else {
    // serial fallback
    off = 0;
    u16*  W1   = (u16*)alloc(90177536);
    u16*  h1s  = (u16*)alloc(33554432);
    u16*  qbs  = (u16*)alloc(33554432);
    u16*  kvbs = (u16*)alloc(16777216);
    u16*  vtbs = (u16*)alloc(8388608);
    float* hmids = (float*)alloc(67108864);
    u16*  gbs  = (u16*)alloc(90177536);
    if (off > ws_size) return;
    u16* wqT  = W1;
    u16* wkvT = W1 + 16777216;
    conv_t<<<dim3(64, 64),  blk, 0, stream>>>(Wq, wqT, 4096, 4096);
    conv_t<<<dim3(16, 64),  blk, 0, stream>>>(Wk, wkvT, 4096, 1024);
    conv_t<<<dim3(16, 64),  blk, 0, stream>>>(Wv, wkvT + 4194304, 4096, 1024);
    rmsnorm_kernel<<<4096, blk, 0, stream>>>(hidden, ln1, h1s);
    gemm256<4096,0><<<256, 512, 131072, stream>>>(h1s, wqT, qbs, nullptr, nullptr, 4096, 4096, 256,
                                                  nullptr, nullptr, 0, 0, 0, 0);
    gemm_bt<0><<<512, blk, 0, stream>>>(h1s, wkvT, kvbs, nullptr, nullptr, 4096, 2048, 4096);
    rope_kernel<<<4096, blk, 0, stream>>>(qbs, kvbs, 2048);
    vtrans<<<dim3(4, 32, 32), dim3(32, 8), 0, stream>>>(kvbs + 1024, vtbs, 2048);
    CJob J0{nullptr, nullptr, 0, 64, 0, 0};
    attn_kernel<<<2048, blk, 0, stream>>>(qbs, kvbs, vtbs, h1s, J0, J0, J0, 2048);
    conv_t<<<dim3(64, 64), blk, 0, stream>>>(Wo, W1, 4096, 4096);
    gemm256<4096,1><<<256, 512, 131072, stream>>>(h1s, W1, hmids, hidden, nullptr, 4096, 4096, 256,
                                                  nullptr, nullptr, 0, 0, 0, 0);
    rmsnorm_kernel<<<4096, blk, 0, stream>>>(hmids, ln2, qbs);
    conv_t<<<dim3(172, 64), blk, 0, stream>>>(Wg, W1, 4096, 11008);
    gemm256<4096,0><<<688, 512, 131072, stream>>>(qbs, W1, gbs, nullptr, nullptr, 4096, 11008, 688,
                                                  nullptr, nullptr, 0, 0, 0, 0);
    conv_t<<<dim3(172, 64), blk, 0, stream>>>(Wu, W1, 4096, 11008);
    gemm256<4096,2><<<688, 512, 131072, stream>>>(qbs, W1, gbs, nullptr, gbs, 4096, 11008, 688,
                                                  nullptr, nullptr, 0, 0, 0, 0);
    conv_t<<<dim3(64, 172), blk, 0, stream>>>(Wd, W1, 11008, 4096);
    gemm256<11008,1><<<256, 512, 131072, stream>>>(gbs, W1, out, hmids, nullptr, 4096, 4096, 256,
                                                   nullptr, nullptr, 0, 0, 0, 0);
  }
}